// Round 12
// baseline (2071.355 us; speedup 1.0000x reference)
//
#include <hip/hip_runtime.h>
#include <hip/hip_bf16.h>
#include <hip/hip_fp8.h>
#include <cstdint>

#define B_   128
#define T_   80
#define E_   100
#define U_   2048
#define G4_  8192

// scales: A-side (x,h) x16, B-side (weights) x32; acc * 1/512 restores z
#define SA_   16.0f
#define SB_   32.0f
#define INV_SASB_ (1.0f / 512.0f)

typedef __attribute__((ext_vector_type(4))) float f32x4;

__device__ __forceinline__ unsigned char f2fp8(float x) {
    __hip_fp8_e4m3 q(x);
    return q.__x;
}

// ---------------- embedding -> A-fragment-packed fp8 X (KB0 = 16 frags) -----
// Xp[((t*8 + mtg)*16 + i)*512 + lane*8 + j] = fp8(SA * x[t][row][k]),
//   row=(mtg>>2)*64+(mtg&3)*16+(lane&15), k = i*32 + (lane>>4)*8 + j  (0 for k>=E)
__global__ __launch_bounds__(256)
void embed_pack(const int* __restrict__ tokens, const float* __restrict__ emb,
                unsigned char* __restrict__ Xp) {
    int gtid = blockIdx.x * 256 + threadIdx.x;   // one 8-byte chunk each
    if (gtid >= T_ * 8 * 16 * 64) return;
    int lane = gtid & 63;
    int rest = gtid >> 6;
    int i    = rest & 15;  rest >>= 4;
    int mtg  = rest & 7;
    int t    = rest >> 3;
    int row  = (mtg >> 2) * 64 + (mtg & 3) * 16 + (lane & 15);
    int k0   = i * 32 + (lane >> 4) * 8;
    const float* erow = emb + (size_t)tokens[row * T_ + t] * E_;
    unsigned char v[8];
#pragma unroll
    for (int j = 0; j < 8; ++j) {
        int e = k0 + j;
        v[j] = f2fp8(e < E_ ? SA_ * erow[e] : 0.f);
    }
    *reinterpret_cast<uint2*>(Xp + (size_t)gtid * 8) = *reinterpret_cast<const uint2*>(v);
}

// ---------------- fused pack of all 5 weight matrices -----------------------
// segments (by blockIdx.x): [0,8192) U0 | [8192,16384) W1 | [16384,24576) U1
//                           [24576,26624) W0 (KB=16) | [26624,28672) Wd
__global__ __launch_bounds__(256)
void pack_all(const float* __restrict__ W0, const float* __restrict__ U0,
              const float* __restrict__ W1, const float* __restrict__ U1,
              const float* __restrict__ Wd,
              unsigned char* __restrict__ W0p, unsigned char* __restrict__ U0p,
              unsigned char* __restrict__ W1p, unsigned char* __restrict__ U1p,
              unsigned char* __restrict__ Wdp) {
    int blk = blockIdx.x;
    const float* W; int K, Ncols, NG, KB; unsigned char* out; int lb;
    if (blk < 8192)       { W = U0; K = U_; Ncols = G4_; NG = 4; KB = 64; out = U0p; lb = blk; }
    else if (blk < 16384) { W = W1; K = U_; Ncols = G4_; NG = 4; KB = 64; out = W1p; lb = blk - 8192; }
    else if (blk < 24576) { W = U1; K = U_; Ncols = G4_; NG = 4; KB = 64; out = U1p; lb = blk - 16384; }
    else if (blk < 26624) { W = W0; K = E_; Ncols = G4_; NG = 4; KB = 16; out = W0p; lb = blk - 24576; }
    else                  { W = Wd; K = U_; Ncols = U_;  NG = 1; KB = 64; out = Wdp; lb = blk - 26624; }

    int gtid = lb * 256 + threadIdx.x;
    int lane = gtid & 63;
    int rest = gtid >> 6;
    int g = rest % NG; rest /= NG;
    int i = rest % KB;
    int ut = rest / KB;
    if (ut >= U_ / 16) return;
    int col = g * U_ + ut * 16 + (lane & 15);
    int k0 = i * 32 + (lane >> 4) * 8;
    unsigned char v[8];
#pragma unroll
    for (int j = 0; j < 8; ++j) {
        int k = k0 + j;
        v[j] = f2fp8(k < K ? SB_ * W[(size_t)k * Ncols + col] : 0.f);
    }
    *reinterpret_cast<uint2*>(out + (size_t)gtid * 8) = *reinterpret_cast<const uint2*>(v);
}

// ---------------- one LSTM layer-step: 16 kq-waves, depth-2 pipeline --------
template<int KB0, int KB1>
__device__ __forceinline__ void lstm_substep(
    const unsigned char* __restrict__ A0p,
    const unsigned char* __restrict__ Wp0,
    const unsigned char* __restrict__ A1p,
    const unsigned char* __restrict__ Wp1,
    const float* __restrict__ bias,
    float* __restrict__ c,
    unsigned char* __restrict__ h_out,
    float (*zs)[64][17],
    int ut, int mh, int tid, int lane, int kq)
{
    constexpr int KBT = KB0 + KB1;    // 80 or 128
    constexpr int NIT = KBT / 16;     // 5 or 8 per wave

    const unsigned char* a0 = A0p + ((size_t)(mh * 4) * KB0) * 512 + lane * 8;
    const unsigned char* a1 = A1p + ((size_t)(mh * 4) * KB1) * 512 + lane * 8;
    const unsigned char* w0 = Wp0 + ((size_t)(ut * KB0) * 4) * 512 + lane * 8;
    const unsigned char* w1 = Wp1 + ((size_t)(ut * KB1) * 4) * 512 + lane * 8;

    const int beg = kq * NIT;

    f32x4 acc[4][4];   // [gate][mt]
#pragma unroll
    for (int g = 0; g < 4; ++g)
#pragma unroll
        for (int mt = 0; mt < 4; ++mt) acc[g][mt] = f32x4{0.f, 0.f, 0.f, 0.f};

    long Ab[2][4], Bb[2][4];    // depth-2 rotation, 32 VGPR

    auto LOAD = [&](int gi, int slot) {
        if (gi < KB0) {
#pragma unroll
            for (int mt = 0; mt < 4; ++mt)
                Ab[slot][mt] = *reinterpret_cast<const long*>(a0 + (size_t)(mt * KB0 + gi) * 512);
#pragma unroll
            for (int g = 0; g < 4; ++g)
                Bb[slot][g] = *reinterpret_cast<const long*>(w0 + (size_t)(gi * 4 + g) * 512);
        } else {
            int ii = gi - KB0;
#pragma unroll
            for (int mt = 0; mt < 4; ++mt)
                Ab[slot][mt] = *reinterpret_cast<const long*>(a1 + (size_t)(mt * KB1 + ii) * 512);
#pragma unroll
            for (int g = 0; g < 4; ++g)
                Bb[slot][g] = *reinterpret_cast<const long*>(w1 + (size_t)(ii * 4 + g) * 512);
        }
    };

    LOAD(beg, 0);
#pragma unroll
    for (int ii = 0; ii < NIT; ++ii) {
        if (ii + 1 < NIT) LOAD(beg + ii + 1, (ii + 1) & 1);
        const int p = ii & 1;
        __builtin_amdgcn_s_setprio(1);
#pragma unroll
        for (int g = 0; g < 4; ++g)
#pragma unroll
            for (int mt = 0; mt < 4; ++mt)
                acc[g][mt] = __builtin_amdgcn_mfma_f32_16x16x32_fp8_fp8(
                    Ab[p][mt], Bb[p][g], acc[g][mt], 0, 0, 0);
        __builtin_amdgcn_s_setprio(0);
    }

    // kq-partial reduction over 16 waves, one gate at a time
    const int lr = tid >> 4;          // 0..63
    const int u  = tid & 15;          // 0..15
    float zg4[4];
#pragma unroll
    for (int g = 0; g < 4; ++g) {
        __syncthreads();
#pragma unroll
        for (int mt = 0; mt < 4; ++mt)
#pragma unroll
            for (int r = 0; r < 4; ++r)
                zs[kq][mt * 16 + (lane >> 4) * 4 + r][lane & 15] = acc[g][mt][r];
        __syncthreads();
        float s = 0.f;
#pragma unroll
        for (int w8 = 0; w8 < 16; ++w8) s += zs[w8][lr][u];
        zg4[g] = s;
    }

    // fused cell update, 1 unit per thread
    const int grow = mh * 64 + lr;
    const int unit = ut * 16 + u;
    float zi = zg4[0] * INV_SASB_ + bias[unit];
    float zf = zg4[1] * INV_SASB_ + bias[U_ + unit];
    float zg = zg4[2] * INV_SASB_ + bias[2 * U_ + unit];
    float zo = zg4[3] * INV_SASB_ + bias[3 * U_ + unit];
    float si = 1.f / (1.f + __expf(-zi));
    float sf = 1.f / (1.f + __expf(-zf));
    float so = 1.f / (1.f + __expf(-zo));
    float tg = tanhf(zg);
    float cc = sf * c[(size_t)grow * U_ + unit] + si * tg;
    c[(size_t)grow * U_ + unit] = cc;

    const int mt = lr >> 4;
    const int cl = lr & 15;
    const int fi = (mh * 4 + mt) * 64 + (unit >> 5);
    const int lp = ((unit >> 3) & 3) * 16 + cl;
    h_out[(size_t)fi * 512 + lp * 8 + (unit & 7)] = f2fp8(SA_ * so * tanhf(cc));
}

// ---------------- LSTM layer-step kernel (grid 256, XCD-swizzled) -----------
template<int KB0, int KB1>
__global__ __launch_bounds__(1024, 4)
void lstm_step_t(const unsigned char* __restrict__ A0p,
                 const unsigned char* __restrict__ Wp0,
                 const unsigned char* __restrict__ A1p,
                 const unsigned char* __restrict__ Wp1,
                 const float* __restrict__ bias,
                 float* __restrict__ c,
                 unsigned char* __restrict__ h_out) {
    __shared__ float zs[16][64][17];   // ~70 KB
    const int tid  = threadIdx.x;
    const int lane = tid & 63;
    const int kq   = tid >> 6;         // 0..15
    const int b    = blockIdx.x;
    const int s    = b >> 3;
    const int ut   = (b & 7) * 16 + (s >> 1);   // xcd owns 16 consecutive ut
    const int mh   = s & 1;
    lstm_substep<KB0, KB1>(A0p, Wp0, A1p, Wp1, bias, c, h_out,
                           zs, ut, mh, tid, lane, kq);
}

// ---------------- head: y = relu((h1 @ Wd)/512 + bd); fp8 operands ----------
__global__ __launch_bounds__(256)
void head_mfma(const unsigned char* __restrict__ h1p,
               const unsigned char* __restrict__ Wdp,
               const float* __restrict__ bd, float* __restrict__ y) {
    const int lane = threadIdx.x & 63;
    const int w    = threadIdx.x >> 6;  // k-split wave
    const int ut   = blockIdx.x & 127;
    const int mh   = blockIdx.x >> 7;

    const unsigned char* ap = h1p + ((size_t)(mh * 4) * 64) * 512 + lane * 8;
    const unsigned char* wp = Wdp + (size_t)(ut * 64 + w * 16) * 512 + lane * 8;

    f32x4 acc[4];
#pragma unroll
    for (int mt = 0; mt < 4; ++mt) acc[mt] = f32x4{0.f, 0.f, 0.f, 0.f};

    auto LOADH = [&](int i, long* a, long& b) {
        b = *reinterpret_cast<const long*>(wp + (size_t)i * 512);
        int kb = w * 16 + i;
#pragma unroll
        for (int mt = 0; mt < 4; ++mt)
            a[mt] = *reinterpret_cast<const long*>(ap + (size_t)(mt * 64 + kb) * 512);
    };

    long aA[4], bA, aB[4], bB;
    LOADH(0, aA, bA);
    for (int i = 0; i < 16; i += 2) {
        LOADH(i + 1, aB, bB);
#pragma unroll
        for (int mt = 0; mt < 4; ++mt)
            acc[mt] = __builtin_amdgcn_mfma_f32_16x16x32_fp8_fp8(aA[mt], bA, acc[mt], 0, 0, 0);
        if (i + 2 < 16) LOADH(i + 2, aA, bA);
#pragma unroll
        for (int mt = 0; mt < 4; ++mt)
            acc[mt] = __builtin_amdgcn_mfma_f32_16x16x32_fp8_fp8(aB[mt], bB, acc[mt], 0, 0, 0);
    }

    __shared__ float zs[4][64][17];
#pragma unroll
    for (int mt = 0; mt < 4; ++mt)
#pragma unroll
        for (int r = 0; r < 4; ++r)
            zs[w][mt * 16 + (lane >> 4) * 4 + r][lane & 15] = acc[mt][r];
    __syncthreads();

    const int tid = threadIdx.x;
    const int lr  = tid >> 2;
    const int u4  = (tid & 3) * 4;
    const int grow = mh * 64 + lr;
    const int gu   = ut * 16 + u4;

    float4 r;
    float* rr = &r.x;
#pragma unroll
    for (int e = 0; e < 4; ++e) {
        float v = (zs[0][lr][u4 + e] + zs[1][lr][u4 + e] +
                   zs[2][lr][u4 + e] + zs[3][lr][u4 + e]) * INV_SASB_ + bd[gu + e];
        rr[e] = v > 0.f ? v : 0.f;
    }
    *reinterpret_cast<float4*>(&y[(size_t)grow * U_ + gu]) = r;
}

// ---------------- out[b] = sigmoid(y[b,:] @ Wo + bo) ----------------
__global__ __launch_bounds__(256)
void head2(const float* __restrict__ y, const float* __restrict__ Wo,
           const float* __restrict__ bo, float* __restrict__ out) {
    __shared__ float red[256];
    const int b = blockIdx.x;
    const int tid = threadIdx.x;
    float s = 0.f;
    for (int u = tid; u < U_; u += 256) s += y[(size_t)b * U_ + u] * Wo[u];
    red[tid] = s;
    __syncthreads();
    for (int off = 128; off > 0; off >>= 1) {
        if (tid < off) red[tid] += red[tid + off];
        __syncthreads();
    }
    if (tid == 0) out[b] = 1.f / (1.f + __expf(-(red[0] + bo[0])));
}

extern "C" void kernel_launch(void* const* d_in, const int* in_sizes, int n_in,
                              void* d_out, int out_size, void* d_ws, size_t ws_size,
                              hipStream_t stream) {
    const int*   tokens = (const int*)  d_in[0];
    const float* emb    = (const float*)d_in[1];
    const float* W0     = (const float*)d_in[2];
    const float* U0     = (const float*)d_in[3];
    const float* b0     = (const float*)d_in[4];
    const float* W1     = (const float*)d_in[5];
    const float* U1     = (const float*)d_in[6];
    const float* b1     = (const float*)d_in[7];
    const float* Wd     = (const float*)d_in[8];
    const float* bd     = (const float*)d_in[9];
    const float* Wo     = (const float*)d_in[10];
    const float* bo     = (const float*)d_in[11];

    // ws layout (bytes); total 64 MB
    char* base = (char*)d_ws;
    unsigned char* h0a = (unsigned char*)(base + 0);         // 256 KB (packed fp8)
    unsigned char* h1a = (unsigned char*)(base + 262144);    // 256 KB
    float*         c0  = (float*)        (base + 524288);    // 1 MB
    float*         c1  = (float*)        (base + 1572864);   // 1 MB
    unsigned char* h0b = (unsigned char*)(base + 2621440);   // 256 KB
    unsigned char* h1b = (unsigned char*)(base + 2883584);   // 256 KB
    unsigned char* Xp  = (unsigned char*)(base + 3145728);   // 5.25 MB (KB0=16)
    float*         yb  = (float*)        (base + 3145728);   // overlays Xp (dead by head)
    unsigned char* W0p = (unsigned char*)(base + 8388608);   // 4 MB
    unsigned char* U0p = (unsigned char*)(base + 12582912);  // 16 MB
    unsigned char* W1p = (unsigned char*)(base + 29360128);  // 16 MB
    unsigned char* U1p = (unsigned char*)(base + 46137344);  // 16 MB
    unsigned char* Wdp = (unsigned char*)(base + 62914560);  // 4 MB

    // zero h0a, h1a, c0, c1 (contiguous 2.56 MB)
    hipMemsetAsync(d_ws, 0, 2621440, stream);

    embed_pack<<<(T_ * 8 * 16 * 64 + 255) / 256, 256, 0, stream>>>(tokens, emb, Xp);
    pack_all<<<28672, 256, 0, stream>>>(W0, U0, W1, U1, Wd,
                                        W0p, U0p, W1p, U1p, Wdp);

    for (int t = 0; t < T_; ++t) {
        const unsigned char* h0in  = (t & 1) ? h0b : h0a;
        unsigned char*       h0out = (t & 1) ? h0a : h0b;
        const unsigned char* h1in  = (t & 1) ? h1b : h1a;
        unsigned char*       h1out = (t & 1) ? h1a : h1b;
        lstm_step_t<16, 64><<<256, 1024, 0, stream>>>(
            Xp + (size_t)t * 8 * 16 * 512, W0p, h0in, U0p, b0, c0, h0out);
        lstm_step_t<64, 64><<<256, 1024, 0, stream>>>(
            h0out, W1p, h1in, U1p, b1, c1, h1out);
    }
    // t=79 (odd) wrote the 'a' buffers
    head_mfma<<<256, 256, 0, stream>>>(h1a, Wdp, bd, yb);
    head2<<<B_, 256, 0, stream>>>(yb, Wo, bo, (float*)d_out);
}

// Round 13
// 1667.682 us; speedup vs baseline: 1.2421x; 1.2421x over previous
//
#include <hip/hip_runtime.h>
#include <hip/hip_bf16.h>
#include <hip/hip_fp8.h>
#include <cstdint>

#define B_   128
#define T_   80
#define E_   100
#define U_   2048
#define G4_  8192

// scales: A-side (x,h) x16, B-side (weights) x32; acc * 1/512 restores z
#define SA_   16.0f
#define SB_   32.0f
#define INV_SASB_ (1.0f / 512.0f)

typedef __attribute__((ext_vector_type(4))) float f32x4;

__device__ __forceinline__ unsigned char f2fp8(float x) {
    __hip_fp8_e4m3 q(x);
    return q.__x;
}

// ---------------- embedding -> A-fragment-packed fp8 X (KB0 = 8 frags) -----
__global__ __launch_bounds__(256)
void embed_pack(const int* __restrict__ tokens, const float* __restrict__ emb,
                unsigned char* __restrict__ Xp) {
    int gtid = blockIdx.x * 256 + threadIdx.x;   // one 8-byte chunk each
    if (gtid >= T_ * 8 * 8 * 64) return;
    int lane = gtid & 63;
    int rest = gtid >> 6;
    int i    = rest & 7;  rest >>= 3;
    int mtg  = rest & 7;
    int t    = rest >> 3;
    int row  = (mtg >> 2) * 64 + (mtg & 3) * 16 + (lane & 15);
    int k0   = i * 32 + (lane >> 4) * 8;
    const float* erow = emb + (size_t)tokens[row * T_ + t] * E_;
    unsigned char v[8];
#pragma unroll
    for (int j = 0; j < 8; ++j) {
        int e = k0 + j;
        v[j] = f2fp8(e < E_ ? SA_ * erow[e] : 0.f);
    }
    *reinterpret_cast<uint2*>(Xp + (size_t)gtid * 8) = *reinterpret_cast<const uint2*>(v);
}

// ---------------- fused pack of all 5 weight matrices -----------------------
// segments (by blockIdx.x): [0,8192) U0 | [8192,16384) W1 | [16384,24576) U1
//                           [24576,25600) W0 (KB=8) | [25600,27648) Wd
__global__ __launch_bounds__(256)
void pack_all(const float* __restrict__ W0, const float* __restrict__ U0,
              const float* __restrict__ W1, const float* __restrict__ U1,
              const float* __restrict__ Wd,
              unsigned char* __restrict__ W0p, unsigned char* __restrict__ U0p,
              unsigned char* __restrict__ W1p, unsigned char* __restrict__ U1p,
              unsigned char* __restrict__ Wdp) {
    int blk = blockIdx.x;
    const float* W; int K, Ncols, NG, KB; unsigned char* out; int lb;
    if (blk < 8192)       { W = U0; K = U_; Ncols = G4_; NG = 4; KB = 64; out = U0p; lb = blk; }
    else if (blk < 16384) { W = W1; K = U_; Ncols = G4_; NG = 4; KB = 64; out = W1p; lb = blk - 8192; }
    else if (blk < 24576) { W = U1; K = U_; Ncols = G4_; NG = 4; KB = 64; out = U1p; lb = blk - 16384; }
    else if (blk < 25600) { W = W0; K = E_; Ncols = G4_; NG = 4; KB = 8;  out = W0p; lb = blk - 24576; }
    else                  { W = Wd; K = U_; Ncols = U_;  NG = 1; KB = 64; out = Wdp; lb = blk - 25600; }

    int gtid = lb * 256 + threadIdx.x;
    int lane = gtid & 63;
    int rest = gtid >> 6;
    int g = rest % NG; rest /= NG;
    int i = rest % KB;
    int ut = rest / KB;
    if (ut >= U_ / 16) return;
    int col = g * U_ + ut * 16 + (lane & 15);
    int k0 = i * 32 + (lane >> 4) * 8;
    unsigned char v[8];
#pragma unroll
    for (int j = 0; j < 8; ++j) {
        int k = k0 + j;
        v[j] = f2fp8(k < K ? SB_ * W[(size_t)k * Ncols + col] : 0.f);
    }
    *reinterpret_cast<uint2*>(out + (size_t)gtid * 8) = *reinterpret_cast<const uint2*>(v);
}

// ---------------- one LSTM layer-step: depth-3 register pipeline ------------
template<int KB0, int KB1>
__device__ __forceinline__ void lstm_substep(
    const unsigned char* __restrict__ A0p,
    const unsigned char* __restrict__ Wp0,
    const unsigned char* __restrict__ A1p,
    const unsigned char* __restrict__ Wp1,
    const float* __restrict__ bias,
    float* __restrict__ c,
    unsigned char* __restrict__ h_out,
    float (*zs)[64][17],
    int ut, int mh, int tid, int lane, int kq)
{
    constexpr int KBT = KB0 + KB1;    // 72 or 128
    constexpr int NIT = KBT / 8;      // 9 or 16 per wave

    const unsigned char* a0 = A0p + ((size_t)(mh * 4) * KB0) * 512 + lane * 8;
    const unsigned char* a1 = A1p + ((size_t)(mh * 4) * KB1) * 512 + lane * 8;
    const unsigned char* w0 = Wp0 + ((size_t)(ut * KB0) * 4) * 512 + lane * 8;
    const unsigned char* w1 = Wp1 + ((size_t)(ut * KB1) * 4) * 512 + lane * 8;

    const int beg = kq * NIT;

    f32x4 acc[4][4];   // [gate][mt]
#pragma unroll
    for (int g = 0; g < 4; ++g)
#pragma unroll
        for (int mt = 0; mt < 4; ++mt) acc[g][mt] = f32x4{0.f, 0.f, 0.f, 0.f};

    long Ab[3][4], Bb[3][4];    // 3-deep rotation, 48 VGPR in fp8

    auto LOAD = [&](int gi, int slot) {
        if (gi < KB0) {
#pragma unroll
            for (int mt = 0; mt < 4; ++mt)
                Ab[slot][mt] = *reinterpret_cast<const long*>(a0 + (size_t)(mt * KB0 + gi) * 512);
#pragma unroll
            for (int g = 0; g < 4; ++g)
                Bb[slot][g] = *reinterpret_cast<const long*>(w0 + (size_t)(gi * 4 + g) * 512);
        } else {
            int ii = gi - KB0;
#pragma unroll
            for (int mt = 0; mt < 4; ++mt)
                Ab[slot][mt] = *reinterpret_cast<const long*>(a1 + (size_t)(mt * KB1 + ii) * 512);
#pragma unroll
            for (int g = 0; g < 4; ++g)
                Bb[slot][g] = *reinterpret_cast<const long*>(w1 + (size_t)(ii * 4 + g) * 512);
        }
    };

    LOAD(beg, 0);
    if (NIT > 1) LOAD(beg + 1, 1);
#pragma unroll
    for (int ii = 0; ii < NIT; ++ii) {
        if (ii + 2 < NIT) LOAD(beg + ii + 2, (ii + 2) % 3);
        const int p = ii % 3;
        __builtin_amdgcn_s_setprio(1);
#pragma unroll
        for (int g = 0; g < 4; ++g)
#pragma unroll
            for (int mt = 0; mt < 4; ++mt)
                acc[g][mt] = __builtin_amdgcn_mfma_f32_16x16x32_fp8_fp8(
                    Ab[p][mt], Bb[p][g], acc[g][mt], 0, 0, 0);
        __builtin_amdgcn_s_setprio(0);
    }

    // kq-partial reduction, one gate at a time (zs padded: stride 17 floats)
    const int lr = tid >> 3;          // 0..63
    const int u0 = (tid & 7) * 2;     // 0,2,..,14
    float zg2[4][2];
#pragma unroll
    for (int g = 0; g < 4; ++g) {
        __syncthreads();
#pragma unroll
        for (int mt = 0; mt < 4; ++mt)
#pragma unroll
            for (int r = 0; r < 4; ++r)
                zs[kq][mt * 16 + (lane >> 4) * 4 + r][lane & 15] = acc[g][mt][r];
        __syncthreads();
        float s0 = 0.f, s1 = 0.f;
#pragma unroll
        for (int w8 = 0; w8 < 8; ++w8) {
            s0 += zs[w8][lr][u0];
            s1 += zs[w8][lr][u0 + 1];
        }
        zg2[g][0] = s0;
        zg2[g][1] = s1;
    }

    // fused cell update for 2 units (rescale acc by 1/(SA*SB) before bias)
    const int grow = mh * 64 + lr;
    const int unit = ut * 16 + u0;
    const float2 bi  = *reinterpret_cast<const float2*>(&bias[unit]);
    const float2 bfv = *reinterpret_cast<const float2*>(&bias[U_ + unit]);
    const float2 bgv = *reinterpret_cast<const float2*>(&bias[2 * U_ + unit]);
    const float2 bov = *reinterpret_cast<const float2*>(&bias[3 * U_ + unit]);
    float2 cv = *reinterpret_cast<float2*>(&c[(size_t)grow * U_ + unit]);

    float cn[2];
    unsigned char hv[2];
#pragma unroll
    for (int e = 0; e < 2; ++e) {
        float zi = zg2[0][e] * INV_SASB_ + (e ? bi.y : bi.x);
        float zf = zg2[1][e] * INV_SASB_ + (e ? bfv.y : bfv.x);
        float zg = zg2[2][e] * INV_SASB_ + (e ? bgv.y : bgv.x);
        float zo = zg2[3][e] * INV_SASB_ + (e ? bov.y : bov.x);
        float si = 1.f / (1.f + __expf(-zi));
        float sf = 1.f / (1.f + __expf(-zf));
        float so = 1.f / (1.f + __expf(-zo));
        float tg = tanhf(zg);
        float cc = sf * (e ? cv.y : cv.x) + si * tg;
        cn[e] = cc;
        hv[e] = f2fp8(SA_ * so * tanhf(cc));
    }
    *reinterpret_cast<float2*>(&c[(size_t)grow * U_ + unit]) = make_float2(cn[0], cn[1]);

    const int mt = lr >> 4;
    const int cl = lr & 15;
    const int fi = (mh * 4 + mt) * 64 + (unit >> 5);
    const int lp = ((unit >> 3) & 3) * 16 + cl;
    uchar2 hv2; hv2.x = hv[0]; hv2.y = hv[1];
    *reinterpret_cast<uchar2*>(&h_out[(size_t)fi * 512 + lp * 8 + (unit & 7)]) = hv2;
}

// ---------------- prologue: L0(0) only (grid 256, XCD-swizzled) -------------
__global__ __launch_bounds__(512)
void lstm_l0_first(const unsigned char* __restrict__ Xp,
                   const unsigned char* __restrict__ W0p,
                   const unsigned char* __restrict__ U0p,
                   const float* __restrict__ b0,
                   float* __restrict__ c0,
                   const unsigned char* __restrict__ h0zero,
                   unsigned char* __restrict__ h0out) {
    __shared__ float zs[8][64][17];
    const int tid  = threadIdx.x;
    const int lane = tid & 63;
    const int kq   = tid >> 6;
    const int b    = blockIdx.x;
    const int s    = b >> 3;
    const int ut   = (b & 7) * 16 + (s >> 1);
    const int mh   = s & 1;
    lstm_substep<8, 64>(Xp, W0p, h0zero, U0p, b0, c0, h0out,
                        zs, ut, mh, tid, lane, kq);
}

// ---------------- fused phase k: L1(k) then L0(k+1), sequential -------------
// grid 256, 512 thr. Both substeps are independent (both consume h0(k)).
__global__ __launch_bounds__(512)
void lstm_phase(const unsigned char* __restrict__ Xp,
                const unsigned char* __restrict__ W0p,
                const unsigned char* __restrict__ U0p,
                const unsigned char* __restrict__ W1p,
                const unsigned char* __restrict__ U1p,
                const float* __restrict__ b0,
                const float* __restrict__ b1,
                float* __restrict__ c0, float* __restrict__ c1,
                const unsigned char* __restrict__ h0cur,
                unsigned char* __restrict__ h0next,
                const unsigned char* __restrict__ h1in,
                unsigned char* __restrict__ h1out,
                int k) {
    __shared__ float zs[8][64][17];
    const int tid  = threadIdx.x;
    const int lane = tid & 63;
    const int kq   = tid >> 6;
    const int b    = blockIdx.x;
    const int s    = b >> 3;
    const int ut   = (b & 7) * 16 + (s >> 1);   // xcd owns 16 consecutive ut
    const int mh   = s & 1;

    // L1(k): h0(k) @ W1 + h1(k-1) @ U1
    lstm_substep<64, 64>(h0cur, W1p, h1in, U1p, b1, c1, h1out,
                         zs, ut, mh, tid, lane, kq);

    // L0(k+1): x(k+1) @ W0 + h0(k) @ U0
    if (k + 1 < T_) {
        lstm_substep<8, 64>(Xp + (size_t)(k + 1) * 8 * 8 * 512, W0p,
                            h0cur, U0p, b0, c0, h0next,
                            zs, ut, mh, tid, lane, kq);
    }
}

// ---------------- head: y = relu((h1 @ Wd)/512 + bd); fp8 operands ----------
__global__ __launch_bounds__(256)
void head_mfma(const unsigned char* __restrict__ h1p,
               const unsigned char* __restrict__ Wdp,
               const float* __restrict__ bd, float* __restrict__ y) {
    const int lane = threadIdx.x & 63;
    const int w    = threadIdx.x >> 6;  // k-split wave
    const int ut   = blockIdx.x & 127;
    const int mh   = blockIdx.x >> 7;

    const unsigned char* ap = h1p + ((size_t)(mh * 4) * 64) * 512 + lane * 8;
    const unsigned char* wp = Wdp + (size_t)(ut * 64 + w * 16) * 512 + lane * 8;

    f32x4 acc[4];
#pragma unroll
    for (int mt = 0; mt < 4; ++mt) acc[mt] = f32x4{0.f, 0.f, 0.f, 0.f};

    auto LOADH = [&](int i, long* a, long& b) {
        b = *reinterpret_cast<const long*>(wp + (size_t)i * 512);
        int kb = w * 16 + i;
#pragma unroll
        for (int mt = 0; mt < 4; ++mt)
            a[mt] = *reinterpret_cast<const long*>(ap + (size_t)(mt * 64 + kb) * 512);
    };

    long aA[4], bA, aB[4], bB;
    LOADH(0, aA, bA);
    for (int i = 0; i < 16; i += 2) {
        LOADH(i + 1, aB, bB);
#pragma unroll
        for (int mt = 0; mt < 4; ++mt)
            acc[mt] = __builtin_amdgcn_mfma_f32_16x16x32_fp8_fp8(aA[mt], bA, acc[mt], 0, 0, 0);
        if (i + 2 < 16) LOADH(i + 2, aA, bA);
#pragma unroll
        for (int mt = 0; mt < 4; ++mt)
            acc[mt] = __builtin_amdgcn_mfma_f32_16x16x32_fp8_fp8(aB[mt], bB, acc[mt], 0, 0, 0);
    }

    __shared__ float zs[4][64][17];
#pragma unroll
    for (int mt = 0; mt < 4; ++mt)
#pragma unroll
        for (int r = 0; r < 4; ++r)
            zs[w][mt * 16 + (lane >> 4) * 4 + r][lane & 15] = acc[mt][r];
    __syncthreads();

    const int tid = threadIdx.x;
    const int lr  = tid >> 2;
    const int u4  = (tid & 3) * 4;
    const int grow = mh * 64 + lr;
    const int gu   = ut * 16 + u4;

    float4 r;
    float* rr = &r.x;
#pragma unroll
    for (int e = 0; e < 4; ++e) {
        float v = (zs[0][lr][u4 + e] + zs[1][lr][u4 + e] +
                   zs[2][lr][u4 + e] + zs[3][lr][u4 + e]) * INV_SASB_ + bd[gu + e];
        rr[e] = v > 0.f ? v : 0.f;
    }
    *reinterpret_cast<float4*>(&y[(size_t)grow * U_ + gu]) = r;
}

// ---------------- out[b] = sigmoid(y[b,:] @ Wo + bo) ----------------
__global__ __launch_bounds__(256)
void head2(const float* __restrict__ y, const float* __restrict__ Wo,
           const float* __restrict__ bo, float* __restrict__ out) {
    __shared__ float red[256];
    const int b = blockIdx.x;
    const int tid = threadIdx.x;
    float s = 0.f;
    for (int u = tid; u < U_; u += 256) s += y[(size_t)b * U_ + u] * Wo[u];
    red[tid] = s;
    __syncthreads();
    for (int off = 128; off > 0; off >>= 1) {
        if (tid < off) red[tid] += red[tid + off];
        __syncthreads();
    }
    if (tid == 0) out[b] = 1.f / (1.f + __expf(-(red[0] + bo[0])));
}

extern "C" void kernel_launch(void* const* d_in, const int* in_sizes, int n_in,
                              void* d_out, int out_size, void* d_ws, size_t ws_size,
                              hipStream_t stream) {
    const int*   tokens = (const int*)  d_in[0];
    const float* emb    = (const float*)d_in[1];
    const float* W0     = (const float*)d_in[2];
    const float* U0     = (const float*)d_in[3];
    const float* b0     = (const float*)d_in[4];
    const float* W1     = (const float*)d_in[5];
    const float* U1     = (const float*)d_in[6];
    const float* b1     = (const float*)d_in[7];
    const float* Wd     = (const float*)d_in[8];
    const float* bd     = (const float*)d_in[9];
    const float* Wo     = (const float*)d_in[10];
    const float* bo     = (const float*)d_in[11];

    // ws layout (bytes); total ~62 MB
    char* base = (char*)d_ws;
    unsigned char* h0a = (unsigned char*)(base + 0);         // 256 KB (packed fp8)
    unsigned char* h1a = (unsigned char*)(base + 262144);    // 256 KB
    float*         c0  = (float*)        (base + 524288);    // 1 MB
    float*         c1  = (float*)        (base + 1572864);   // 1 MB
    unsigned char* h0b = (unsigned char*)(base + 2621440);   // 256 KB
    unsigned char* h1b = (unsigned char*)(base + 2883584);   // 256 KB
    unsigned char* Xp  = (unsigned char*)(base + 3145728);   // 2.62 MB
    float*         yb  = (float*)        (base + 3145728);   // overlays Xp (dead by head)
    unsigned char* W0p = (unsigned char*)(base + 5767168);   // 2 MB
    unsigned char* U0p = (unsigned char*)(base + 7864320);   // 16 MB
    unsigned char* W1p = (unsigned char*)(base + 24641536);  // 16 MB
    unsigned char* U1p = (unsigned char*)(base + 41418752);  // 16 MB
    unsigned char* Wdp = (unsigned char*)(base + 58195968);  // 4 MB

    // zero h0a, h1a, c0, c1 (contiguous 2.56 MB)
    hipMemsetAsync(d_ws, 0, 2621440, stream);

    embed_pack<<<(T_ * 8 * 8 * 64 + 255) / 256, 256, 0, stream>>>(tokens, emb, Xp);
    pack_all<<<27648, 256, 0, stream>>>(W0, U0, W1, U1, Wd,
                                        W0p, U0p, W1p, U1p, Wdp);

    // prologue: L0(0): x(0) + h0a(=0) -> h0b
    lstm_l0_first<<<256, 512, 0, stream>>>(Xp, W0p, U0p, b0, c0, h0a, h0b);

    // fused phases: phase k = { L1(k), L0(k+1) }
    for (int k = 0; k < T_; ++k) {
        const unsigned char* h0cur  = (k & 1) ? h0a : h0b;
        unsigned char*       h0next = (k & 1) ? h0b : h0a;   // written for k+1
        const unsigned char* h1in   = (k & 1) ? h1b : h1a;
        unsigned char*       h1out  = (k & 1) ? h1a : h1b;
        lstm_phase<<<256, 512, 0, stream>>>(Xp, W0p, U0p, W1p, U1p,
                                            b0, b1, c0, c1,
                                            h0cur, h0next, h1in, h1out, k);
    }
    // h1(79): 79 odd -> h1a
    head_mfma<<<256, 256, 0, stream>>>(h1a, Wdp, bd, yb);
    head2<<<B_, 256, 0, stream>>>(yb, Wo, bo, (float*)d_out);
}

// Round 14
// 1640.997 us; speedup vs baseline: 1.2623x; 1.0163x over previous
//
#include <hip/hip_runtime.h>
#include <hip/hip_bf16.h>
#include <hip/hip_fp8.h>
#include <cstdint>

#define B_   128
#define T_   80
#define E_   100
#define U_   2048
#define G4_  8192

// scales: A-side (x,h) x16, B-side (weights) x32; acc * 1/512 restores z
#define SA_   16.0f
#define SB_   32.0f
#define INV_SASB_ (1.0f / 512.0f)

typedef __attribute__((ext_vector_type(4))) float f32x4;

__device__ __forceinline__ unsigned char f2fp8(float x) {
    __hip_fp8_e4m3 q(x);
    return q.__x;
}

// ---------------- embedding -> A-fragment-packed fp8 X (KB0 = 8 frags) -----
__global__ __launch_bounds__(256)
void embed_pack(const int* __restrict__ tokens, const float* __restrict__ emb,
                unsigned char* __restrict__ Xp) {
    int gtid = blockIdx.x * 256 + threadIdx.x;   // one 8-byte chunk each
    if (gtid >= T_ * 8 * 8 * 64) return;
    int lane = gtid & 63;
    int rest = gtid >> 6;
    int i    = rest & 7;  rest >>= 3;
    int mtg  = rest & 7;
    int t    = rest >> 3;
    int row  = (mtg >> 2) * 64 + (mtg & 3) * 16 + (lane & 15);
    int k0   = i * 32 + (lane >> 4) * 8;
    const float* erow = emb + (size_t)tokens[row * T_ + t] * E_;
    unsigned char v[8];
#pragma unroll
    for (int j = 0; j < 8; ++j) {
        int e = k0 + j;
        v[j] = f2fp8(e < E_ ? SA_ * erow[e] : 0.f);
    }
    *reinterpret_cast<uint2*>(Xp + (size_t)gtid * 8) = *reinterpret_cast<const uint2*>(v);
}

// ---------------- fused pack, LDS-staged coalesced reads --------------------
// Block = (matrix segment, gate g, ut4 = 4 units-of-16, k-frag i).
// Stage [32 k][64 col] fp32 coalesced -> LDS; gather+quantize -> 4 fragments.
// segments (by blockIdx.x): [0,8192) U0 | [8192,16384) W1 | [16384,24576) U1
//                           [24576,25600) W0 (KB=8) | [25600,27648) Wd
__global__ __launch_bounds__(256)
void pack_all(const float* __restrict__ W0, const float* __restrict__ U0,
              const float* __restrict__ W1, const float* __restrict__ U1,
              const float* __restrict__ Wd,
              unsigned char* __restrict__ W0p, unsigned char* __restrict__ U0p,
              unsigned char* __restrict__ W1p, unsigned char* __restrict__ U1p,
              unsigned char* __restrict__ Wdp) {
    __shared__ float st[32][65];   // +1 pad: 2-way max bank aliasing
    const int tid = threadIdx.x;
    int blk = blockIdx.x;
    const float* W; int K, Ncols, NG, KB; unsigned char* out; int lb;
    if (blk < 8192)       { W = U0; K = U_; Ncols = G4_; NG = 4; KB = 64; out = U0p; lb = blk; }
    else if (blk < 16384) { W = W1; K = U_; Ncols = G4_; NG = 4; KB = 64; out = W1p; lb = blk - 8192; }
    else if (blk < 24576) { W = U1; K = U_; Ncols = G4_; NG = 4; KB = 64; out = U1p; lb = blk - 16384; }
    else if (blk < 25600) { W = W0; K = E_; Ncols = G4_; NG = 4; KB = 8;  out = W0p; lb = blk - 24576; }
    else                  { W = Wd; K = U_; Ncols = U_;  NG = 1; KB = 64; out = Wdp; lb = blk - 25600; }

    const int i    = lb % KB;       // k-fragment index
    const int rest = lb / KB;
    const int ut4  = rest & 31;     // group of 4 ut
    const int g    = rest >> 5;     // gate (0 for Wd)
    const int cb   = g * U_ + ut4 * 64;

    // stage: thread t loads row r = t>>3, cols (t&7)*8 .. +8 (two float4)
    {
        const int r  = tid >> 3;
        const int c0 = (tid & 7) * 8;
        const int k  = i * 32 + r;
        float a[8];
        if (k < K) {
            const float* src = W + (size_t)k * Ncols + cb + c0;
            *reinterpret_cast<float4*>(&a[0]) = *reinterpret_cast<const float4*>(src);
            *reinterpret_cast<float4*>(&a[4]) = *reinterpret_cast<const float4*>(src + 4);
        } else {
#pragma unroll
            for (int j = 0; j < 8; ++j) a[j] = 0.f;
        }
#pragma unroll
        for (int j = 0; j < 8; ++j) st[r][c0 + j] = a[j];
    }
    __syncthreads();

    // emit: wave uu = tid>>6 handles unit ut4*4+uu; frag layout as before:
    // out[(((ut*KB + i)*NG + g)*64 + lane)*8 + j] = fp8(SB*W[i*32+(lane>>4)*8+j][g*U+ut*16+(lane&15)])
    const int uu   = tid >> 6;
    const int lane = tid & 63;
    const int cl   = lane & 15;
    const int kg   = lane >> 4;
    unsigned char v[8];
#pragma unroll
    for (int j = 0; j < 8; ++j)
        v[j] = f2fp8(SB_ * st[kg * 8 + j][uu * 16 + cl]);
    const int ut = ut4 * 4 + uu;
    unsigned char* dst = out + (((size_t)(ut * KB + i) * NG + g) * 64 + lane) * 8;
    *reinterpret_cast<uint2*>(dst) = *reinterpret_cast<const uint2*>(v);
}

// ---------------- one LSTM layer-step: depth-3 register pipeline ------------
template<int KB0, int KB1>
__device__ __forceinline__ void lstm_substep(
    const unsigned char* __restrict__ A0p,
    const unsigned char* __restrict__ Wp0,
    const unsigned char* __restrict__ A1p,
    const unsigned char* __restrict__ Wp1,
    const float* __restrict__ bias,
    float* __restrict__ c,
    unsigned char* __restrict__ h_out,
    float (*zs)[64][17],
    int ut, int mh, int tid, int lane, int kq)
{
    constexpr int KBT = KB0 + KB1;    // 72 or 128
    constexpr int NIT = KBT / 8;      // 9 or 16 per wave

    const unsigned char* a0 = A0p + ((size_t)(mh * 4) * KB0) * 512 + lane * 8;
    const unsigned char* a1 = A1p + ((size_t)(mh * 4) * KB1) * 512 + lane * 8;
    const unsigned char* w0 = Wp0 + ((size_t)(ut * KB0) * 4) * 512 + lane * 8;
    const unsigned char* w1 = Wp1 + ((size_t)(ut * KB1) * 4) * 512 + lane * 8;

    const int beg = kq * NIT;

    f32x4 acc[4][4];   // [gate][mt]
#pragma unroll
    for (int g = 0; g < 4; ++g)
#pragma unroll
        for (int mt = 0; mt < 4; ++mt) acc[g][mt] = f32x4{0.f, 0.f, 0.f, 0.f};

    long Ab[3][4], Bb[3][4];    // 3-deep rotation, 48 VGPR in fp8

    auto LOAD = [&](int gi, int slot) {
        if (gi < KB0) {
#pragma unroll
            for (int mt = 0; mt < 4; ++mt)
                Ab[slot][mt] = *reinterpret_cast<const long*>(a0 + (size_t)(mt * KB0 + gi) * 512);
#pragma unroll
            for (int g = 0; g < 4; ++g)
                Bb[slot][g] = *reinterpret_cast<const long*>(w0 + (size_t)(gi * 4 + g) * 512);
        } else {
            int ii = gi - KB0;
#pragma unroll
            for (int mt = 0; mt < 4; ++mt)
                Ab[slot][mt] = *reinterpret_cast<const long*>(a1 + (size_t)(mt * KB1 + ii) * 512);
#pragma unroll
            for (int g = 0; g < 4; ++g)
                Bb[slot][g] = *reinterpret_cast<const long*>(w1 + (size_t)(ii * 4 + g) * 512);
        }
    };

    LOAD(beg, 0);
    if (NIT > 1) LOAD(beg + 1, 1);
#pragma unroll
    for (int ii = 0; ii < NIT; ++ii) {
        if (ii + 2 < NIT) LOAD(beg + ii + 2, (ii + 2) % 3);
        const int p = ii % 3;
        __builtin_amdgcn_s_setprio(1);
#pragma unroll
        for (int g = 0; g < 4; ++g)
#pragma unroll
            for (int mt = 0; mt < 4; ++mt)
                acc[g][mt] = __builtin_amdgcn_mfma_f32_16x16x32_fp8_fp8(
                    Ab[p][mt], Bb[p][g], acc[g][mt], 0, 0, 0);
        __builtin_amdgcn_s_setprio(0);
    }

    // kq-partial reduction, one gate at a time (zs padded: stride 17 floats)
    const int lr = tid >> 3;          // 0..63
    const int u0 = (tid & 7) * 2;     // 0,2,..,14
    float zg2[4][2];
#pragma unroll
    for (int g = 0; g < 4; ++g) {
        __syncthreads();
#pragma unroll
        for (int mt = 0; mt < 4; ++mt)
#pragma unroll
            for (int r = 0; r < 4; ++r)
                zs[kq][mt * 16 + (lane >> 4) * 4 + r][lane & 15] = acc[g][mt][r];
        __syncthreads();
        float s0 = 0.f, s1 = 0.f;
#pragma unroll
        for (int w8 = 0; w8 < 8; ++w8) {
            s0 += zs[w8][lr][u0];
            s1 += zs[w8][lr][u0 + 1];
        }
        zg2[g][0] = s0;
        zg2[g][1] = s1;
    }

    // fused cell update for 2 units (rescale acc by 1/(SA*SB) before bias)
    const int grow = mh * 64 + lr;
    const int unit = ut * 16 + u0;
    const float2 bi  = *reinterpret_cast<const float2*>(&bias[unit]);
    const float2 bfv = *reinterpret_cast<const float2*>(&bias[U_ + unit]);
    const float2 bgv = *reinterpret_cast<const float2*>(&bias[2 * U_ + unit]);
    const float2 bov = *reinterpret_cast<const float2*>(&bias[3 * U_ + unit]);
    float2 cv = *reinterpret_cast<float2*>(&c[(size_t)grow * U_ + unit]);

    float cn[2];
    unsigned char hv[2];
#pragma unroll
    for (int e = 0; e < 2; ++e) {
        float zi = zg2[0][e] * INV_SASB_ + (e ? bi.y : bi.x);
        float zf = zg2[1][e] * INV_SASB_ + (e ? bfv.y : bfv.x);
        float zg = zg2[2][e] * INV_SASB_ + (e ? bgv.y : bgv.x);
        float zo = zg2[3][e] * INV_SASB_ + (e ? bov.y : bov.x);
        float si = 1.f / (1.f + __expf(-zi));
        float sf = 1.f / (1.f + __expf(-zf));
        float so = 1.f / (1.f + __expf(-zo));
        float tg = tanhf(zg);
        float cc = sf * (e ? cv.y : cv.x) + si * tg;
        cn[e] = cc;
        hv[e] = f2fp8(SA_ * so * tanhf(cc));
    }
    *reinterpret_cast<float2*>(&c[(size_t)grow * U_ + unit]) = make_float2(cn[0], cn[1]);

    const int mt = lr >> 4;
    const int cl = lr & 15;
    const int fi = (mh * 4 + mt) * 64 + (unit >> 5);
    const int lp = ((unit >> 3) & 3) * 16 + cl;
    uchar2 hv2; hv2.x = hv[0]; hv2.y = hv[1];
    *reinterpret_cast<uchar2*>(&h_out[(size_t)fi * 512 + lp * 8 + (unit & 7)]) = hv2;
}

// ---------------- prologue: L0(0) only (grid 256, XCD-swizzled) -------------
__global__ __launch_bounds__(512)
void lstm_l0_first(const unsigned char* __restrict__ Xp,
                   const unsigned char* __restrict__ W0p,
                   const unsigned char* __restrict__ U0p,
                   const float* __restrict__ b0,
                   float* __restrict__ c0,
                   const unsigned char* __restrict__ h0zero,
                   unsigned char* __restrict__ h0out) {
    __shared__ float zs[8][64][17];
    const int tid  = threadIdx.x;
    const int lane = tid & 63;
    const int kq   = tid >> 6;
    const int b    = blockIdx.x;
    const int s    = b >> 3;
    const int ut   = (b & 7) * 16 + (s >> 1);
    const int mh   = s & 1;
    lstm_substep<8, 64>(Xp, W0p, h0zero, U0p, b0, c0, h0out,
                        zs, ut, mh, tid, lane, kq);
}

// ---------------- fused phase k: L1(k) then L0(k+1), sequential -------------
// grid 256, 512 thr. Both substeps are independent (both consume h0(k)).
__global__ __launch_bounds__(512)
void lstm_phase(const unsigned char* __restrict__ Xp,
                const unsigned char* __restrict__ W0p,
                const unsigned char* __restrict__ U0p,
                const unsigned char* __restrict__ W1p,
                const unsigned char* __restrict__ U1p,
                const float* __restrict__ b0,
                const float* __restrict__ b1,
                float* __restrict__ c0, float* __restrict__ c1,
                const unsigned char* __restrict__ h0cur,
                unsigned char* __restrict__ h0next,
                const unsigned char* __restrict__ h1in,
                unsigned char* __restrict__ h1out,
                int k) {
    __shared__ float zs[8][64][17];
    const int tid  = threadIdx.x;
    const int lane = tid & 63;
    const int kq   = tid >> 6;
    const int b    = blockIdx.x;
    const int s    = b >> 3;
    const int ut   = (b & 7) * 16 + (s >> 1);   // xcd owns 16 consecutive ut
    const int mh   = s & 1;

    // L1(k): h0(k) @ W1 + h1(k-1) @ U1
    lstm_substep<64, 64>(h0cur, W1p, h1in, U1p, b1, c1, h1out,
                         zs, ut, mh, tid, lane, kq);

    // L0(k+1): x(k+1) @ W0 + h0(k) @ U0
    if (k + 1 < T_) {
        lstm_substep<8, 64>(Xp + (size_t)(k + 1) * 8 * 8 * 512, W0p,
                            h0cur, U0p, b0, c0, h0next,
                            zs, ut, mh, tid, lane, kq);
    }
}

// ---------------- head: y = relu((h1 @ Wd)/512 + bd); fp8 operands ----------
__global__ __launch_bounds__(256)
void head_mfma(const unsigned char* __restrict__ h1p,
               const unsigned char* __restrict__ Wdp,
               const float* __restrict__ bd, float* __restrict__ y) {
    const int lane = threadIdx.x & 63;
    const int w    = threadIdx.x >> 6;  // k-split wave
    const int ut   = blockIdx.x & 127;
    const int mh   = blockIdx.x >> 7;

    const unsigned char* ap = h1p + ((size_t)(mh * 4) * 64) * 512 + lane * 8;
    const unsigned char* wp = Wdp + (size_t)(ut * 64 + w * 16) * 512 + lane * 8;

    f32x4 acc[4];
#pragma unroll
    for (int mt = 0; mt < 4; ++mt) acc[mt] = f32x4{0.f, 0.f, 0.f, 0.f};

    auto LOADH = [&](int i, long* a, long& b) {
        b = *reinterpret_cast<const long*>(wp + (size_t)i * 512);
        int kb = w * 16 + i;
#pragma unroll
        for (int mt = 0; mt < 4; ++mt)
            a[mt] = *reinterpret_cast<const long*>(ap + (size_t)(mt * 64 + kb) * 512);
    };

    long aA[4], bA, aB[4], bB;
    LOADH(0, aA, bA);
    for (int i = 0; i < 16; i += 2) {
        LOADH(i + 1, aB, bB);
#pragma unroll
        for (int mt = 0; mt < 4; ++mt)
            acc[mt] = __builtin_amdgcn_mfma_f32_16x16x32_fp8_fp8(aA[mt], bA, acc[mt], 0, 0, 0);
        if (i + 2 < 16) LOADH(i + 2, aA, bA);
#pragma unroll
        for (int mt = 0; mt < 4; ++mt)
            acc[mt] = __builtin_amdgcn_mfma_f32_16x16x32_fp8_fp8(aB[mt], bB, acc[mt], 0, 0, 0);
    }

    __shared__ float zs[4][64][17];
#pragma unroll
    for (int mt = 0; mt < 4; ++mt)
#pragma unroll
        for (int r = 0; r < 4; ++r)
            zs[w][mt * 16 + (lane >> 4) * 4 + r][lane & 15] = acc[mt][r];
    __syncthreads();

    const int tid = threadIdx.x;
    const int lr  = tid >> 2;
    const int u4  = (tid & 3) * 4;
    const int grow = mh * 64 + lr;
    const int gu   = ut * 16 + u4;

    float4 r;
    float* rr = &r.x;
#pragma unroll
    for (int e = 0; e < 4; ++e) {
        float v = (zs[0][lr][u4 + e] + zs[1][lr][u4 + e] +
                   zs[2][lr][u4 + e] + zs[3][lr][u4 + e]) * INV_SASB_ + bd[gu + e];
        rr[e] = v > 0.f ? v : 0.f;
    }
    *reinterpret_cast<float4*>(&y[(size_t)grow * U_ + gu]) = r;
}

// ---------------- out[b] = sigmoid(y[b,:] @ Wo + bo) ----------------
__global__ __launch_bounds__(256)
void head2(const float* __restrict__ y, const float* __restrict__ Wo,
           const float* __restrict__ bo, float* __restrict__ out) {
    __shared__ float red[256];
    const int b = blockIdx.x;
    const int tid = threadIdx.x;
    float s = 0.f;
    for (int u = tid; u < U_; u += 256) s += y[(size_t)b * U_ + u] * Wo[u];
    red[tid] = s;
    __syncthreads();
    for (int off = 128; off > 0; off >>= 1) {
        if (tid < off) red[tid] += red[tid + off];
        __syncthreads();
    }
    if (tid == 0) out[b] = 1.f / (1.f + __expf(-(red[0] + bo[0])));
}

extern "C" void kernel_launch(void* const* d_in, const int* in_sizes, int n_in,
                              void* d_out, int out_size, void* d_ws, size_t ws_size,
                              hipStream_t stream) {
    const int*   tokens = (const int*)  d_in[0];
    const float* emb    = (const float*)d_in[1];
    const float* W0     = (const float*)d_in[2];
    const float* U0     = (const float*)d_in[3];
    const float* b0     = (const float*)d_in[4];
    const float* W1     = (const float*)d_in[5];
    const float* U1     = (const float*)d_in[6];
    const float* b1     = (const float*)d_in[7];
    const float* Wd     = (const float*)d_in[8];
    const float* bd     = (const float*)d_in[9];
    const float* Wo     = (const float*)d_in[10];
    const float* bo     = (const float*)d_in[11];

    // ws layout (bytes); total ~62 MB
    char* base = (char*)d_ws;
    unsigned char* h0a = (unsigned char*)(base + 0);         // 256 KB (packed fp8)
    unsigned char* h1a = (unsigned char*)(base + 262144);    // 256 KB
    float*         c0  = (float*)        (base + 524288);    // 1 MB
    float*         c1  = (float*)        (base + 1572864);   // 1 MB
    unsigned char* h0b = (unsigned char*)(base + 2621440);   // 256 KB
    unsigned char* h1b = (unsigned char*)(base + 2883584);   // 256 KB
    unsigned char* Xp  = (unsigned char*)(base + 3145728);   // 2.62 MB
    float*         yb  = (float*)        (base + 3145728);   // overlays Xp (dead by head)
    unsigned char* W0p = (unsigned char*)(base + 5767168);   // 2 MB
    unsigned char* U0p = (unsigned char*)(base + 7864320);   // 16 MB
    unsigned char* W1p = (unsigned char*)(base + 24641536);  // 16 MB
    unsigned char* U1p = (unsigned char*)(base + 41418752);  // 16 MB
    unsigned char* Wdp = (unsigned char*)(base + 58195968);  // 4 MB

    // zero h0a, h1a, c0, c1 (contiguous 2.56 MB)
    hipMemsetAsync(d_ws, 0, 2621440, stream);

    embed_pack<<<(T_ * 8 * 8 * 64 + 255) / 256, 256, 0, stream>>>(tokens, emb, Xp);
    pack_all<<<27648, 256, 0, stream>>>(W0, U0, W1, U1, Wd,
                                        W0p, U0p, W1p, U1p, Wdp);

    // prologue: L0(0): x(0) + h0a(=0) -> h0b
    lstm_l0_first<<<256, 512, 0, stream>>>(Xp, W0p, U0p, b0, c0, h0a, h0b);

    // fused phases: phase k = { L1(k), L0(k+1) }
    for (int k = 0; k < T_; ++k) {
        const unsigned char* h0cur  = (k & 1) ? h0a : h0b;
        unsigned char*       h0next = (k & 1) ? h0b : h0a;   // written for k+1
        const unsigned char* h1in   = (k & 1) ? h1b : h1a;
        unsigned char*       h1out  = (k & 1) ? h1a : h1b;
        lstm_phase<<<256, 512, 0, stream>>>(Xp, W0p, U0p, W1p, U1p,
                                            b0, b1, c0, c1,
                                            h0cur, h0next, h1in, h1out, k);
    }
    // h1(79): 79 odd -> h1a
    head_mfma<<<256, 256, 0, stream>>>(h1a, Wdp, bd, yb);
    head2<<<B_, 256, 0, stream>>>(yb, Wo, bo, (float*)d_out);
}

// Round 15
// 1305.451 us; speedup vs baseline: 1.5867x; 1.2570x over previous
//
#include <hip/hip_runtime.h>
#include <hip/hip_bf16.h>
#include <hip/hip_fp8.h>
#include <cstdint>

#define B_   128
#define T_   80
#define E_   100
#define U_   2048
#define G4_  8192

// scales: A-side (x,h) fp8 x16; B-side (weights) fp4 x64; acc * 1/1024
#define SA_    16.0f
#define SB4_   64.0f
#define INV_S_ (1.0f / 1024.0f)
#define SCL1_  0x7F7F7F7F   // E8M0 = 127 -> 2^0 per 32-block (x4 packed)

typedef __attribute__((ext_vector_type(4))) float f32x4;
typedef __attribute__((ext_vector_type(8))) int   i32x8;
typedef __attribute__((ext_vector_type(4))) int   i32x4;

__device__ __forceinline__ unsigned char f2fp8(float x) {
    __hip_fp8_e4m3 q(x);
    return q.__x;
}

// fp4 e2m1 quantize (round to nearest): values {0,.5,1,1.5,2,3,4,6}
__device__ __forceinline__ unsigned int q4(float x) {
    float a = fabsf(x);
    unsigned int s = (x < 0.f) ? 8u : 0u;
    unsigned int c = a < 0.25f ? 0u : a < 0.75f ? 1u : a < 1.25f ? 2u :
                     a < 1.75f ? 3u : a < 2.5f  ? 4u : a < 3.5f  ? 5u :
                     a < 5.0f  ? 6u : 7u;
    return s | c;
}

// ---------------- embedding -> fp8 A-frag128 X: 1 window of K=128 -----------
// Xp[(t*8+mtg)*2048 + lane*32 + e] = fp8(SA*x[t][row][k]), k=(lane>>4)*32+e
__global__ __launch_bounds__(256)
void embed_pack(const int* __restrict__ tokens, const float* __restrict__ emb,
                unsigned char* __restrict__ Xp) {
    int gtid = blockIdx.x * 256 + threadIdx.x;   // one 8-byte chunk each
    if (gtid >= T_ * 8 * 64 * 4) return;
    int eb   = gtid & 3;
    int lane = (gtid >> 2) & 63;
    int mtg  = (gtid >> 8) & 7;
    int t    = gtid >> 11;
    int row  = (mtg >> 2) * 64 + (mtg & 3) * 16 + (lane & 15);
    const float* erow = emb + (size_t)tokens[row * T_ + t] * E_;
    unsigned char v[8];
#pragma unroll
    for (int j = 0; j < 8; ++j) {
        int k = (lane >> 4) * 32 + eb * 8 + j;
        v[j] = (k < E_) ? f2fp8(SA_ * erow[k]) : 0;
    }
    unsigned char* dst = Xp + ((size_t)(t * 8 + mtg)) * 2048 + lane * 32 + eb * 8;
    *reinterpret_cast<uint2*>(dst) = *reinterpret_cast<const uint2*>(v);
}

// ---------------- fused fp4 pack of all 5 weight matrices -------------------
// B-frag128: byte b of lane l = fp4 pair (e=2b lo, 2b+1 hi),
//   k = W*128 + (l>>4)*32 + e, col = g*U + ut*16 + (l&15)
// out addr: Wp[((ut*NW + W)*NG + g)*1024 + lane*16]
// blocks: U0 [0,2048) NW16 | W1 [2048,4096) | U1 [4096,6144) |
//         W0 [6144,6272) NW1 | Wd [6272,6784) NW16 NG1
__global__ __launch_bounds__(256)
void pack_all(const float* __restrict__ W0, const float* __restrict__ U0,
              const float* __restrict__ W1, const float* __restrict__ U1,
              const float* __restrict__ Wd,
              unsigned char* __restrict__ W0p, unsigned char* __restrict__ U0p,
              unsigned char* __restrict__ W1p, unsigned char* __restrict__ U1p,
              unsigned char* __restrict__ Wdp) {
    __shared__ float st[128][65];
    const int tid = threadIdx.x;
    int blk = blockIdx.x;
    const float* W; int K, Ncols, NG, NW; unsigned char* out; int lb;
    if (blk < 2048)      { W = U0; K = U_; Ncols = G4_; NG = 4; NW = 16; out = U0p; lb = blk; }
    else if (blk < 4096) { W = W1; K = U_; Ncols = G4_; NG = 4; NW = 16; out = W1p; lb = blk - 2048; }
    else if (blk < 6144) { W = U1; K = U_; Ncols = G4_; NG = 4; NW = 16; out = U1p; lb = blk - 4096; }
    else if (blk < 6272) { W = W0; K = E_; Ncols = G4_; NG = 4; NW = 1;  out = W0p; lb = blk - 6144; }
    else                 { W = Wd; K = U_; Ncols = U_;  NG = 1; NW = 16; out = Wdp; lb = blk - 6272; }

    const int Wm  = lb % NW;
    const int r2  = lb / NW;
    const int ut4 = r2 & 31;     // 4 ut (64 cols)
    const int g   = r2 >> 5;
    const int cb  = g * U_ + ut4 * 64;

    // stage 128 k-rows x 64 cols (fp32), coalesced 64B-per-row-quad reads
    {
        const int q  = tid & 3;          // col quad: cols q*16..q*16+16
        const int r0 = tid >> 2;         // rows r0, r0+64
#pragma unroll
        for (int rr = r0; rr < 128; rr += 64) {
            const int k = Wm * 128 + rr;
            float a[16];
            if (k < K) {
                const float* src = W + (size_t)k * Ncols + cb + q * 16;
#pragma unroll
                for (int f = 0; f < 4; ++f)
                    *reinterpret_cast<float4*>(&a[f * 4]) =
                        *reinterpret_cast<const float4*>(src + f * 4);
            } else {
#pragma unroll
                for (int j = 0; j < 16; ++j) a[j] = 0.f;
            }
#pragma unroll
            for (int j = 0; j < 16; ++j) st[rr][q * 16 + j] = a[j];
        }
    }
    __syncthreads();

    // emit one fragment lane-slot (16 B) per thread
    const int ut_in = tid >> 6;
    const int lane  = tid & 63;
    const int cl    = lane & 15;
    const int kg    = lane >> 4;
    unsigned char v[16];
#pragma unroll
    for (int b = 0; b < 16; ++b) {
        float v0 = st[kg * 32 + 2 * b][ut_in * 16 + cl];
        float v1 = st[kg * 32 + 2 * b + 1][ut_in * 16 + cl];
        v[b] = (unsigned char)(q4(SB4_ * v0) | (q4(SB4_ * v1) << 4));
    }
    const int ut = ut4 * 4 + ut_in;
    unsigned char* dst = out + (((size_t)(ut * NW + Wm)) * NG + g) * 1024 + lane * 16;
    *reinterpret_cast<uint4*>(dst) = *reinterpret_cast<const uint4*>(v);
}

// ---------------- MFMA helper: A fp8 (8 regs), B fp4 (4 regs, hi=0) ---------
#define MFMA_SET(ASET, BSET)                                                     \
    {                                                                            \
        __builtin_amdgcn_s_setprio(1);                                           \
        _Pragma("unroll")                                                        \
        for (int g = 0; g < 4; ++g) {                                            \
            i32x8 bf = {BSET[g][0], BSET[g][1], BSET[g][2], BSET[g][3],          \
                        0, 0, 0, 0};                                             \
            _Pragma("unroll")                                                    \
            for (int mt = 0; mt < 4; ++mt)                                       \
                acc[g][mt] = __builtin_amdgcn_mfma_scale_f32_16x16x128_f8f6f4(   \
                    ASET[mt], bf, acc[g][mt], 0, 4, 0, SCL1_, 0, SCL1_);         \
        }                                                                        \
        __builtin_amdgcn_s_setprio(0);                                           \
    }

// ---------------- one LSTM layer-step: K=128 windows, stride-8 per wave -----
template<int NW0, int NW1>
__device__ __forceinline__ void lstm_substep(
    const unsigned char* __restrict__ A0p,   // fp8 frag128 [8 mtg][NW0][2048]
    const unsigned char* __restrict__ Wp0,   // fp4 frag128 [128 ut][NW0][4][1024]
    const unsigned char* __restrict__ A1p,
    const unsigned char* __restrict__ Wp1,
    const float* __restrict__ bias,
    float* __restrict__ c,
    unsigned char* __restrict__ h_out,       // fp8 frag128 [8 mtg][16][2048]
    float (*zs)[64][17],
    int ut, int mh, int tid, int lane, int kq)
{
    constexpr int NW = NW0 + NW1;
    const unsigned char* a0 = A0p + ((size_t)(mh * 4) * NW0) * 2048 + lane * 32;
    const unsigned char* a1 = A1p + ((size_t)(mh * 4) * NW1) * 2048 + lane * 32;
    const unsigned char* b0 = Wp0 + ((size_t)(ut * NW0) * 4) * 1024 + lane * 16;
    const unsigned char* b1 = Wp1 + ((size_t)(ut * NW1) * 4) * 1024 + lane * 16;

    f32x4 acc[4][4];   // [gate][mt]
#pragma unroll
    for (int g = 0; g < 4; ++g)
#pragma unroll
        for (int mt = 0; mt < 4; ++mt) acc[g][mt] = f32x4{0.f, 0.f, 0.f, 0.f};

    i32x8 Aa[4]; i32x4 Ba[4];   // named set A
    i32x8 Ab[4]; i32x4 Bb[4];   // named set B

#define LD(SETA, SETB, w)                                                        \
    {                                                                            \
        if ((w) < NW0) {                                                         \
            _Pragma("unroll")                                                    \
            for (int mt = 0; mt < 4; ++mt)                                       \
                SETA[mt] = *reinterpret_cast<const i32x8*>(                      \
                    a0 + (size_t)(mt * NW0 + (w)) * 2048);                       \
            _Pragma("unroll")                                                    \
            for (int g = 0; g < 4; ++g)                                          \
                SETB[g] = *reinterpret_cast<const i32x4*>(                       \
                    b0 + (size_t)((w) * 4 + g) * 1024);                          \
        } else {                                                                 \
            int ww = (w) - NW0;                                                  \
            _Pragma("unroll")                                                    \
            for (int mt = 0; mt < 4; ++mt)                                       \
                SETA[mt] = *reinterpret_cast<const i32x8*>(                      \
                    a1 + (size_t)(mt * NW1 + ww) * 2048);                        \
            _Pragma("unroll")                                                    \
            for (int g = 0; g < 4; ++g)                                          \
                SETB[g] = *reinterpret_cast<const i32x4*>(                       \
                    b1 + (size_t)(ww * 4 + g) * 1024);                           \
        }                                                                        \
    }

    // windows kq, kq+8, kq+16, ... ; depth-2 ping-pong with named sets
    int w = kq;
    if (w < NW) {
        LD(Aa, Ba, w);
        while (true) {
            int w2 = w + 8;
            if (w2 < NW) LD(Ab, Bb, w2);
            MFMA_SET(Aa, Ba);
            if (w2 >= NW) break;
            int w3 = w2 + 8;
            if (w3 < NW) LD(Aa, Ba, w3);
            MFMA_SET(Ab, Bb);
            if (w3 >= NW) break;
            w = w3;
        }
    }
#undef LD

    // kq-partial reduction, one gate at a time (zs stride 17 floats)
    const int lr = tid >> 3;          // 0..63
    const int u0 = (tid & 7) * 2;     // 0,2,..,14
    float zg2[4][2];
#pragma unroll
    for (int g = 0; g < 4; ++g) {
        __syncthreads();
#pragma unroll
        for (int mt = 0; mt < 4; ++mt)
#pragma unroll
            for (int r = 0; r < 4; ++r)
                zs[kq][mt * 16 + (lane >> 4) * 4 + r][lane & 15] = acc[g][mt][r];
        __syncthreads();
        float s0 = 0.f, s1 = 0.f;
#pragma unroll
        for (int w8 = 0; w8 < 8; ++w8) {
            s0 += zs[w8][lr][u0];
            s1 += zs[w8][lr][u0 + 1];
        }
        zg2[g][0] = s0;
        zg2[g][1] = s1;
    }

    // fused cell update for 2 units
    const int grow = mh * 64 + lr;
    const int unit = ut * 16 + u0;
    const float2 bi  = *reinterpret_cast<const float2*>(&bias[unit]);
    const float2 bfv = *reinterpret_cast<const float2*>(&bias[U_ + unit]);
    const float2 bgv = *reinterpret_cast<const float2*>(&bias[2 * U_ + unit]);
    const float2 bov = *reinterpret_cast<const float2*>(&bias[3 * U_ + unit]);
    float2 cv = *reinterpret_cast<float2*>(&c[(size_t)grow * U_ + unit]);

    float cn[2];
    unsigned char hv[2];
#pragma unroll
    for (int e = 0; e < 2; ++e) {
        float zi = zg2[0][e] * INV_S_ + (e ? bi.y : bi.x);
        float zf = zg2[1][e] * INV_S_ + (e ? bfv.y : bfv.x);
        float zg = zg2[2][e] * INV_S_ + (e ? bgv.y : bgv.x);
        float zo = zg2[3][e] * INV_S_ + (e ? bov.y : bov.x);
        float si = 1.f / (1.f + __expf(-zi));
        float sf = 1.f / (1.f + __expf(-zf));
        float so = 1.f / (1.f + __expf(-zo));
        float tg = tanhf(zg);
        float cc = sf * (e ? cv.y : cv.x) + si * tg;
        cn[e] = cc;
        hv[e] = f2fp8(SA_ * so * tanhf(cc));
    }
    *reinterpret_cast<float2*>(&c[(size_t)grow * U_ + unit]) = make_float2(cn[0], cn[1]);

    // packed fp8 h write in A-frag128 layout (NW=16 windows)
    const int mt = lr >> 4;
    const int cl = lr & 15;
    const int Wh = unit >> 7;
    const int lg = (unit >> 5) & 3;
    const int e0 = unit & 31;            // even
    size_t fr = (size_t)(mh * 4 + mt) * 16 + Wh;
    uchar2 hv2; hv2.x = hv[0]; hv2.y = hv[1];
    *reinterpret_cast<uchar2*>(&h_out[fr * 2048 + (lg * 16 + cl) * 32 + e0]) = hv2;
}

// ---------------- prologue: L0(0) only (grid 256, XCD-swizzled) -------------
__global__ __launch_bounds__(512, 2)
void lstm_l0_first(const unsigned char* __restrict__ Xp,
                   const unsigned char* __restrict__ W0p,
                   const unsigned char* __restrict__ U0p,
                   const float* __restrict__ b0,
                   float* __restrict__ c0,
                   const unsigned char* __restrict__ h0zero,
                   unsigned char* __restrict__ h0out) {
    __shared__ float zs[8][64][17];
    const int tid  = threadIdx.x;
    const int lane = tid & 63;
    const int kq   = tid >> 6;
    const int b    = blockIdx.x;
    const int s    = b >> 3;
    const int ut   = (b & 7) * 16 + (s >> 1);
    const int mh   = s & 1;
    lstm_substep<1, 16>(Xp, W0p, h0zero, U0p, b0, c0, h0out,
                        zs, ut, mh, tid, lane, kq);
}

// ---------------- fused phase k: L1(k) then L0(k+1), sequential -------------
__global__ __launch_bounds__(512, 2)
void lstm_phase(const unsigned char* __restrict__ Xp,
                const unsigned char* __restrict__ W0p,
                const unsigned char* __restrict__ U0p,
                const unsigned char* __restrict__ W1p,
                const unsigned char* __restrict__ U1p,
                const float* __restrict__ b0,
                const float* __restrict__ b1,
                float* __restrict__ c0, float* __restrict__ c1,
                const unsigned char* __restrict__ h0cur,
                unsigned char* __restrict__ h0next,
                const unsigned char* __restrict__ h1in,
                unsigned char* __restrict__ h1out,
                int k) {
    __shared__ float zs[8][64][17];
    const int tid  = threadIdx.x;
    const int lane = tid & 63;
    const int kq   = tid >> 6;
    const int b    = blockIdx.x;
    const int s    = b >> 3;
    const int ut   = (b & 7) * 16 + (s >> 1);   // xcd owns 16 consecutive ut
    const int mh   = s & 1;

    // L1(k): h0(k) @ W1 + h1(k-1) @ U1
    lstm_substep<16, 16>(h0cur, W1p, h1in, U1p, b1, c1, h1out,
                         zs, ut, mh, tid, lane, kq);

    // L0(k+1): x(k+1) @ W0 + h0(k) @ U0
    if (k + 1 < T_) {
        lstm_substep<1, 16>(Xp + (size_t)(k + 1) * 8 * 2048, W0p,
                            h0cur, U0p, b0, c0, h0next,
                            zs, ut, mh, tid, lane, kq);
    }
}

// ---------------- head: y = relu((h1 @ Wd)/1024 + bd); fp8 x fp4 ------------
__global__ __launch_bounds__(256)
void head_mfma(const unsigned char* __restrict__ h1p,
               const unsigned char* __restrict__ Wdp,
               const float* __restrict__ bd, float* __restrict__ y) {
    const int lane = threadIdx.x & 63;
    const int w    = threadIdx.x >> 6;  // k-split wave (windows w, w+4, w+8, w+12)
    const int ut   = blockIdx.x & 127;
    const int mh   = blockIdx.x >> 7;

    const unsigned char* ap = h1p + ((size_t)(mh * 4) * 16) * 2048 + lane * 32;
    const unsigned char* wp = Wdp + ((size_t)(ut * 16)) * 1024 + lane * 16;

    f32x4 acc[4];
#pragma unroll
    for (int mt = 0; mt < 4; ++mt) acc[mt] = f32x4{0.f, 0.f, 0.f, 0.f};

#pragma unroll
    for (int wi = 0; wi < 4; ++wi) {
        const int W = w + wi * 4;
        i32x4 bq = *reinterpret_cast<const i32x4*>(wp + (size_t)W * 1024);
        i32x8 bf = {bq[0], bq[1], bq[2], bq[3], 0, 0, 0, 0};
#pragma unroll
        for (int mt = 0; mt < 4; ++mt) {
            i32x8 a = *reinterpret_cast<const i32x8*>(ap + (size_t)(mt * 16 + W) * 2048);
            acc[mt] = __builtin_amdgcn_mfma_scale_f32_16x16x128_f8f6f4(
                a, bf, acc[mt], 0, 4, 0, SCL1_, 0, SCL1_);
        }
    }

    __shared__ float zs[4][64][17];
#pragma unroll
    for (int mt = 0; mt < 4; ++mt)
#pragma unroll
        for (int r = 0; r < 4; ++r)
            zs[w][mt * 16 + (lane >> 4) * 4 + r][lane & 15] = acc[mt][r];
    __syncthreads();

    const int tid = threadIdx.x;
    const int lr  = tid >> 2;
    const int u4  = (tid & 3) * 4;
    const int grow = mh * 64 + lr;
    const int gu   = ut * 16 + u4;

    float4 r;
    float* rr = &r.x;
#pragma unroll
    for (int e = 0; e < 4; ++e) {
        float v = (zs[0][lr][u4 + e] + zs[1][lr][u4 + e] +
                   zs[2][lr][u4 + e] + zs[3][lr][u4 + e]) * INV_S_ + bd[gu + e];
        rr[e] = v > 0.f ? v : 0.f;
    }
    *reinterpret_cast<float4*>(&y[(size_t)grow * U_ + gu]) = r;
}

// ---------------- out[b] = sigmoid(y[b,:] @ Wo + bo) ----------------
__global__ __launch_bounds__(256)
void head2(const float* __restrict__ y, const float* __restrict__ Wo,
           const float* __restrict__ bo, float* __restrict__ out) {
    __shared__ float red[256];
    const int b = blockIdx.x;
    const int tid = threadIdx.x;
    float s = 0.f;
    for (int u = tid; u < U_; u += 256) s += y[(size_t)b * U_ + u] * Wo[u];
    red[tid] = s;
    __syncthreads();
    for (int off = 128; off > 0; off >>= 1) {
        if (tid < off) red[tid] += red[tid + off];
        __syncthreads();
    }
    if (tid == 0) out[b] = 1.f / (1.f + __expf(-(red[0] + bo[0])));
}

extern "C" void kernel_launch(void* const* d_in, const int* in_sizes, int n_in,
                              void* d_out, int out_size, void* d_ws, size_t ws_size,
                              hipStream_t stream) {
    const int*   tokens = (const int*)  d_in[0];
    const float* emb    = (const float*)d_in[1];
    const float* W0     = (const float*)d_in[2];
    const float* U0     = (const float*)d_in[3];
    const float* b0     = (const float*)d_in[4];
    const float* W1     = (const float*)d_in[5];
    const float* U1     = (const float*)d_in[6];
    const float* b1     = (const float*)d_in[7];
    const float* Wd     = (const float*)d_in[8];
    const float* bd     = (const float*)d_in[9];
    const float* Wo     = (const float*)d_in[10];
    const float* bo     = (const float*)d_in[11];

    // ws layout (bytes); total ~32 MB
    char* base = (char*)d_ws;
    unsigned char* h0a = (unsigned char*)(base + 0);         // 256 KB (fp8 frag128)
    unsigned char* h1a = (unsigned char*)(base + 262144);    // 256 KB
    float*         c0  = (float*)        (base + 524288);    // 1 MB
    float*         c1  = (float*)        (base + 1572864);   // 1 MB
    unsigned char* h0b = (unsigned char*)(base + 2621440);   // 256 KB
    unsigned char* h1b = (unsigned char*)(base + 2883584);   // 256 KB
    unsigned char* Xp  = (unsigned char*)(base + 3145728);   // 1.25 MB
    float*         yb  = (float*)        (base + 3145728);   // overlays Xp (dead by head)
    unsigned char* W0p = (unsigned char*)(base + 4456448);   // 512 KB (fp4)
    unsigned char* U0p = (unsigned char*)(base + 4980736);   // 8 MB (fp4)
    unsigned char* W1p = (unsigned char*)(base + 13369344);  // 8 MB (fp4)
    unsigned char* U1p = (unsigned char*)(base + 21757952);  // 8 MB (fp4)
    unsigned char* Wdp = (unsigned char*)(base + 30146560);  // 2 MB (fp4)

    // zero h0a, h1a, c0, c1 (contiguous 2.56 MB)
    hipMemsetAsync(d_ws, 0, 2621440, stream);

    embed_pack<<<(T_ * 8 * 64 * 4 + 255) / 256, 256, 0, stream>>>(tokens, emb, Xp);
    pack_all<<<6784, 256, 0, stream>>>(W0, U0, W1, U1, Wd,
                                       W0p, U0p, W1p, U1p, Wdp);

    // prologue: L0(0): x(0) + h0a(=0) -> h0b
    lstm_l0_first<<<256, 512, 0, stream>>>(Xp, W0p, U0p, b0, c0, h0a, h0b);

    // fused phases: phase k = { L1(k), L0(k+1) }
    for (int k = 0; k < T_; ++k) {
        const unsigned char* h0cur  = (k & 1) ? h0a : h0b;
        unsigned char*       h0next = (k & 1) ? h0b : h0a;   // written for k+1
        const unsigned char* h1in   = (k & 1) ? h1b : h1a;
        unsigned char*       h1out  = (k & 1) ? h1a : h1b;
        lstm_phase<<<256, 512, 0, stream>>>(Xp, W0p, U0p, W1p, U1p,
                                            b0, b1, c0, c1,
                                            h0cur, h0next, h1in, h1out, k);
    }
    // h1(79): 79 odd -> h1a
    head_mfma<<<256, 256, 0, stream>>>(h1a, Wdp, bd, yb);
    head2<<<B_, 256, 0, stream>>>(yb, Wo, bo, (float*)d_out);
}

// Round 16
// 1165.564 us; speedup vs baseline: 1.7771x; 1.1200x over previous
//
#include <hip/hip_runtime.h>
#include <hip/hip_bf16.h>
#include <hip/hip_fp8.h>
#include <cstdint>

#define B_   128
#define T_   80
#define E_   100
#define U_   2048
#define G4_  8192

// scales: A-side (x,h) fp8 x16; B-side (weights) fp4 x64; acc * 1/1024
#define SA_    16.0f
#define SB4_   64.0f
#define INV_S_ (1.0f / 1024.0f)
#define SCL1_  0x7F7F7F7F   // E8M0 = 127 -> 2^0 per 32-block (x4 packed)

typedef __attribute__((ext_vector_type(4))) float f32x4;
typedef __attribute__((ext_vector_type(8))) int   i32x8;
typedef __attribute__((ext_vector_type(4))) int   i32x4;

__device__ __forceinline__ unsigned char f2fp8(float x) {
    __hip_fp8_e4m3 q(x);
    return q.__x;
}

// fp4 e2m1 quantize (round to nearest): values {0,.5,1,1.5,2,3,4,6}
__device__ __forceinline__ unsigned int q4(float x) {
    float a = fabsf(x);
    unsigned int s = (x < 0.f) ? 8u : 0u;
    unsigned int c = a < 0.25f ? 0u : a < 0.75f ? 1u : a < 1.25f ? 2u :
                     a < 1.75f ? 3u : a < 2.5f  ? 4u : a < 3.5f  ? 5u :
                     a < 5.0f  ? 6u : 7u;
    return s | c;
}

// ---------------- embedding -> fp8 A-frag128 X: 1 window of K=128 -----------
__global__ __launch_bounds__(256)
void embed_pack(const int* __restrict__ tokens, const float* __restrict__ emb,
                unsigned char* __restrict__ Xp) {
    int gtid = blockIdx.x * 256 + threadIdx.x;   // one 8-byte chunk each
    if (gtid >= T_ * 8 * 64 * 4) return;
    int eb   = gtid & 3;
    int lane = (gtid >> 2) & 63;
    int mtg  = (gtid >> 8) & 7;
    int t    = gtid >> 11;
    int row  = (mtg >> 2) * 64 + (mtg & 3) * 16 + (lane & 15);
    const float* erow = emb + (size_t)tokens[row * T_ + t] * E_;
    unsigned char v[8];
#pragma unroll
    for (int j = 0; j < 8; ++j) {
        int k = (lane >> 4) * 32 + eb * 8 + j;
        v[j] = (k < E_) ? f2fp8(SA_ * erow[k]) : 0;
    }
    unsigned char* dst = Xp + ((size_t)(t * 8 + mtg)) * 2048 + lane * 32 + eb * 8;
    *reinterpret_cast<uint2*>(dst) = *reinterpret_cast<const uint2*>(v);
}

// ---------------- fused fp4 pack of all 5 weight matrices -------------------
__global__ __launch_bounds__(256)
void pack_all(const float* __restrict__ W0, const float* __restrict__ U0,
              const float* __restrict__ W1, const float* __restrict__ U1,
              const float* __restrict__ Wd,
              unsigned char* __restrict__ W0p, unsigned char* __restrict__ U0p,
              unsigned char* __restrict__ W1p, unsigned char* __restrict__ U1p,
              unsigned char* __restrict__ Wdp) {
    __shared__ float st[128][65];
    const int tid = threadIdx.x;
    int blk = blockIdx.x;
    const float* W; int K, Ncols, NG, NW; unsigned char* out; int lb;
    if (blk < 2048)      { W = U0; K = U_; Ncols = G4_; NG = 4; NW = 16; out = U0p; lb = blk; }
    else if (blk < 4096) { W = W1; K = U_; Ncols = G4_; NG = 4; NW = 16; out = W1p; lb = blk - 2048; }
    else if (blk < 6144) { W = U1; K = U_; Ncols = G4_; NG = 4; NW = 16; out = U1p; lb = blk - 4096; }
    else if (blk < 6272) { W = W0; K = E_; Ncols = G4_; NG = 4; NW = 1;  out = W0p; lb = blk - 6144; }
    else                 { W = Wd; K = U_; Ncols = U_;  NG = 1; NW = 16; out = Wdp; lb = blk - 6272; }

    const int Wm  = lb % NW;
    const int r2  = lb / NW;
    const int ut4 = r2 & 31;     // 4 ut (64 cols)
    const int g   = r2 >> 5;
    const int cb  = g * U_ + ut4 * 64;

    {
        const int q  = tid & 3;
        const int r0 = tid >> 2;
#pragma unroll
        for (int rr = r0; rr < 128; rr += 64) {
            const int k = Wm * 128 + rr;
            float a[16];
            if (k < K) {
                const float* src = W + (size_t)k * Ncols + cb + q * 16;
#pragma unroll
                for (int f = 0; f < 4; ++f)
                    *reinterpret_cast<float4*>(&a[f * 4]) =
                        *reinterpret_cast<const float4*>(src + f * 4);
            } else {
#pragma unroll
                for (int j = 0; j < 16; ++j) a[j] = 0.f;
            }
#pragma unroll
            for (int j = 0; j < 16; ++j) st[rr][q * 16 + j] = a[j];
        }
    }
    __syncthreads();

    const int ut_in = tid >> 6;
    const int lane  = tid & 63;
    const int cl    = lane & 15;
    const int kg    = lane >> 4;
    unsigned char v[16];
#pragma unroll
    for (int b = 0; b < 16; ++b) {
        float v0 = st[kg * 32 + 2 * b][ut_in * 16 + cl];
        float v1 = st[kg * 32 + 2 * b + 1][ut_in * 16 + cl];
        v[b] = (unsigned char)(q4(SB4_ * v0) | (q4(SB4_ * v1) << 4));
    }
    const int ut = ut4 * 4 + ut_in;
    unsigned char* dst = out + (((size_t)(ut * NW + Wm)) * NG + g) * 1024 + lane * 16;
    *reinterpret_cast<uint4*>(dst) = *reinterpret_cast<const uint4*>(v);
}

// ---------------- MFMA helper: A fp8 (8 regs), B fp4 (4 regs, hi=0) ---------
#define MFMA_SET(ASET, BSET)                                                     \
    {                                                                            \
        __builtin_amdgcn_s_setprio(1);                                           \
        _Pragma("unroll")                                                        \
        for (int g = 0; g < 4; ++g) {                                            \
            i32x8 bf = {BSET[g][0], BSET[g][1], BSET[g][2], BSET[g][3],          \
                        0, 0, 0, 0};                                             \
            _Pragma("unroll")                                                    \
            for (int mt = 0; mt < 4; ++mt)                                       \
                acc[g][mt] = __builtin_amdgcn_mfma_scale_f32_16x16x128_f8f6f4(   \
                    ASET[mt], bf, acc[g][mt], 0, 4, 0, SCL1_, 0, SCL1_);         \
        }                                                                        \
        __builtin_amdgcn_s_setprio(0);                                           \
    }

// ---------------- one LSTM layer-step: K=128 windows, depth-3 static --------
template<int NW0, int NW1>
__device__ __forceinline__ void lstm_substep(
    const unsigned char* __restrict__ A0p,
    const unsigned char* __restrict__ Wp0,
    const unsigned char* __restrict__ A1p,
    const unsigned char* __restrict__ Wp1,
    const float* __restrict__ bias,
    float* __restrict__ c,
    unsigned char* __restrict__ h_out,
    float (*zs)[2][64][17],
    int ut, int mh, int tid, int lane, int kq)
{
    constexpr int NW = NW0 + NW1;     // 17 or 32
    const unsigned char* a0 = A0p + ((size_t)(mh * 4) * NW0) * 2048 + lane * 32;
    const unsigned char* a1 = A1p + ((size_t)(mh * 4) * NW1) * 2048 + lane * 32;
    const unsigned char* b0 = Wp0 + ((size_t)(ut * NW0) * 4) * 1024 + lane * 16;
    const unsigned char* b1 = Wp1 + ((size_t)(ut * NW1) * 4) * 1024 + lane * 16;

    f32x4 acc[4][4];   // [gate][mt]
#pragma unroll
    for (int g = 0; g < 4; ++g)
#pragma unroll
        for (int mt = 0; mt < 4; ++mt) acc[g][mt] = f32x4{0.f, 0.f, 0.f, 0.f};

#define LD(SETA, SETB, w)                                                        \
    {                                                                            \
        if ((w) < NW0) {                                                         \
            _Pragma("unroll")                                                    \
            for (int mt = 0; mt < 4; ++mt)                                       \
                SETA[mt] = *reinterpret_cast<const i32x8*>(                      \
                    a0 + (size_t)(mt * NW0 + (w)) * 2048);                       \
            _Pragma("unroll")                                                    \
            for (int g = 0; g < 4; ++g)                                          \
                SETB[g] = *reinterpret_cast<const i32x4*>(                       \
                    b0 + (size_t)((w) * 4 + g) * 1024);                          \
        } else {                                                                 \
            int ww = (w) - NW0;                                                  \
            _Pragma("unroll")                                                    \
            for (int mt = 0; mt < 4; ++mt)                                       \
                SETA[mt] = *reinterpret_cast<const i32x8*>(                      \
                    a1 + (size_t)(mt * NW1 + ww) * 2048);                        \
            _Pragma("unroll")                                                    \
            for (int g = 0; g < 4; ++g)                                          \
                SETB[g] = *reinterpret_cast<const i32x4*>(                       \
                    b1 + (size_t)(ww * 4 + g) * 1024);                           \
        }                                                                        \
    }

    // depth-3 static window schedule; wave kq owns windows kq, kq+8, kq+16, kq+24
    {
        i32x8 A0s[4], A1s[4], A2s[4];
        i32x4 B0s[4], B1s[4], B2s[4];
        if constexpr (NW == 32) {
            LD(A0s, B0s, kq);
            LD(A1s, B1s, kq + 8);
            LD(A2s, B2s, kq + 16);
            MFMA_SET(A0s, B0s);
            LD(A0s, B0s, kq + 24);
            MFMA_SET(A1s, B1s);
            MFMA_SET(A2s, B2s);
            MFMA_SET(A0s, B0s);
        } else {
            LD(A0s, B0s, kq);
            LD(A1s, B1s, kq + 8);
            const bool tail = (kq + 16 < NW);
            if (tail) LD(A2s, B2s, kq + 16);
            MFMA_SET(A0s, B0s);
            MFMA_SET(A1s, B1s);
            if (tail) MFMA_SET(A2s, B2s);
        }
    }
#undef LD

    // kq-partial reduction: 2 gates per round, 4 barriers total
    const int lr = tid >> 3;          // 0..63
    const int u0 = (tid & 7) * 2;     // 0,2,..,14
    float zg2[4][2];
#pragma unroll
    for (int rnd = 0; rnd < 2; ++rnd) {
        __syncthreads();
#pragma unroll
        for (int gg = 0; gg < 2; ++gg) {
            const int g = rnd * 2 + gg;
#pragma unroll
            for (int mt = 0; mt < 4; ++mt)
#pragma unroll
                for (int r = 0; r < 4; ++r)
                    zs[kq][gg][mt * 16 + (lane >> 4) * 4 + r][lane & 15] = acc[g][mt][r];
        }
        __syncthreads();
#pragma unroll
        for (int gg = 0; gg < 2; ++gg) {
            float s0 = 0.f, s1 = 0.f;
#pragma unroll
            for (int w8 = 0; w8 < 8; ++w8) {
                s0 += zs[w8][gg][lr][u0];
                s1 += zs[w8][gg][lr][u0 + 1];
            }
            zg2[rnd * 2 + gg][0] = s0;
            zg2[rnd * 2 + gg][1] = s1;
        }
    }

    // fused cell update for 2 units
    const int grow = mh * 64 + lr;
    const int unit = ut * 16 + u0;
    const float2 bi  = *reinterpret_cast<const float2*>(&bias[unit]);
    const float2 bfv = *reinterpret_cast<const float2*>(&bias[U_ + unit]);
    const float2 bgv = *reinterpret_cast<const float2*>(&bias[2 * U_ + unit]);
    const float2 bov = *reinterpret_cast<const float2*>(&bias[3 * U_ + unit]);
    float2 cv = *reinterpret_cast<float2*>(&c[(size_t)grow * U_ + unit]);

    float cn[2];
    unsigned char hv[2];
#pragma unroll
    for (int e = 0; e < 2; ++e) {
        float zi = zg2[0][e] * INV_S_ + (e ? bi.y : bi.x);
        float zf = zg2[1][e] * INV_S_ + (e ? bfv.y : bfv.x);
        float zg = zg2[2][e] * INV_S_ + (e ? bgv.y : bgv.x);
        float zo = zg2[3][e] * INV_S_ + (e ? bov.y : bov.x);
        float si = 1.f / (1.f + __expf(-zi));
        float sf = 1.f / (1.f + __expf(-zf));
        float so = 1.f / (1.f + __expf(-zo));
        float tg = tanhf(zg);
        float cc = sf * (e ? cv.y : cv.x) + si * tg;
        cn[e] = cc;
        hv[e] = f2fp8(SA_ * so * tanhf(cc));
    }
    *reinterpret_cast<float2*>(&c[(size_t)grow * U_ + unit]) = make_float2(cn[0], cn[1]);

    // packed fp8 h write in A-frag128 layout (16 windows)
    const int mt = lr >> 4;
    const int cl = lr & 15;
    const int Wh = unit >> 7;
    const int lg = (unit >> 5) & 3;
    const int e0 = unit & 31;            // even
    size_t fr = (size_t)(mh * 4 + mt) * 16 + Wh;
    uchar2 hv2; hv2.x = hv[0]; hv2.y = hv[1];
    *reinterpret_cast<uchar2*>(&h_out[fr * 2048 + (lg * 16 + cl) * 32 + e0]) = hv2;
}

// ---------------- prologue: L0(0) only (grid 256, XCD-swizzled) -------------
__global__ __launch_bounds__(512)
void lstm_l0_first(const unsigned char* __restrict__ Xp,
                   const unsigned char* __restrict__ W0p,
                   const unsigned char* __restrict__ U0p,
                   const float* __restrict__ b0,
                   float* __restrict__ c0,
                   const unsigned char* __restrict__ h0zero,
                   unsigned char* __restrict__ h0out) {
    __shared__ float zs[8][2][64][17];
    const int tid  = threadIdx.x;
    const int lane = tid & 63;
    const int kq   = tid >> 6;
    const int b    = blockIdx.x;
    const int s    = b >> 3;
    const int ut   = (b & 7) * 16 + (s >> 1);
    const int mh   = s & 1;
    lstm_substep<1, 16>(Xp, W0p, h0zero, U0p, b0, c0, h0out,
                        zs, ut, mh, tid, lane, kq);
}

// ---------------- fused phase k: L1(k) then L0(k+1), sequential -------------
__global__ __launch_bounds__(512)
void lstm_phase(const unsigned char* __restrict__ Xp,
                const unsigned char* __restrict__ W0p,
                const unsigned char* __restrict__ U0p,
                const unsigned char* __restrict__ W1p,
                const unsigned char* __restrict__ U1p,
                const float* __restrict__ b0,
                const float* __restrict__ b1,
                float* __restrict__ c0, float* __restrict__ c1,
                const unsigned char* __restrict__ h0cur,
                unsigned char* __restrict__ h0next,
                const unsigned char* __restrict__ h1in,
                unsigned char* __restrict__ h1out,
                int k) {
    __shared__ float zs[8][2][64][17];
    const int tid  = threadIdx.x;
    const int lane = tid & 63;
    const int kq   = tid >> 6;
    const int b    = blockIdx.x;
    const int s    = b >> 3;
    const int ut   = (b & 7) * 16 + (s >> 1);   // xcd owns 16 consecutive ut
    const int mh   = s & 1;

    // L1(k): h0(k) @ W1 + h1(k-1) @ U1
    lstm_substep<16, 16>(h0cur, W1p, h1in, U1p, b1, c1, h1out,
                         zs, ut, mh, tid, lane, kq);

    // L0(k+1): x(k+1) @ W0 + h0(k) @ U0
    if (k + 1 < T_) {
        lstm_substep<1, 16>(Xp + (size_t)(k + 1) * 8 * 2048, W0p,
                            h0cur, U0p, b0, c0, h0next,
                            zs, ut, mh, tid, lane, kq);
    }
}

// ---------------- head: y = relu((h1 @ Wd)/1024 + bd); fp8 x fp4 ------------
__global__ __launch_bounds__(256)
void head_mfma(const unsigned char* __restrict__ h1p,
               const unsigned char* __restrict__ Wdp,
               const float* __restrict__ bd, float* __restrict__ y) {
    const int lane = threadIdx.x & 63;
    const int w    = threadIdx.x >> 6;  // k-split wave
    const int ut   = blockIdx.x & 127;
    const int mh   = blockIdx.x >> 7;

    const unsigned char* ap = h1p + ((size_t)(mh * 4) * 16) * 2048 + lane * 32;
    const unsigned char* wp = Wdp + ((size_t)(ut * 16)) * 1024 + lane * 16;

    f32x4 acc[4];
#pragma unroll
    for (int mt = 0; mt < 4; ++mt) acc[mt] = f32x4{0.f, 0.f, 0.f, 0.f};

#pragma unroll
    for (int wi = 0; wi < 4; ++wi) {
        const int W = w + wi * 4;
        i32x4 bq = *reinterpret_cast<const i32x4*>(wp + (size_t)W * 1024);
        i32x8 bf = {bq[0], bq[1], bq[2], bq[3], 0, 0, 0, 0};
#pragma unroll
        for (int mt = 0; mt < 4; ++mt) {
            i32x8 a = *reinterpret_cast<const i32x8*>(ap + (size_t)(mt * 16 + W) * 2048);
            acc[mt] = __builtin_amdgcn_mfma_scale_f32_16x16x128_f8f6f4(
                a, bf, acc[mt], 0, 4, 0, SCL1_, 0, SCL1_);
        }
    }

    __shared__ float zs[4][64][17];
#pragma unroll
    for (int mt = 0; mt < 4; ++mt)
#pragma unroll
        for (int r = 0; r < 4; ++r)
            zs[w][mt * 16 + (lane >> 4) * 4 + r][lane & 15] = acc[mt][r];
    __syncthreads();

    const int tid = threadIdx.x;
    const int lr  = tid >> 2;
    const int u4  = (tid & 3) * 4;
    const int grow = mh * 64 + lr;
    const int gu   = ut * 16 + u4;

    float4 r;
    float* rr = &r.x;
#pragma unroll
    for (int e = 0; e < 4; ++e) {
        float v = (zs[0][lr][u4 + e] + zs[1][lr][u4 + e] +
                   zs[2][lr][u4 + e] + zs[3][lr][u4 + e]) * INV_S_ + bd[gu + e];
        rr[e] = v > 0.f ? v : 0.f;
    }
    *reinterpret_cast<float4*>(&y[(size_t)grow * U_ + gu]) = r;
}

// ---------------- out[b] = sigmoid(y[b,:] @ Wo + bo) ----------------
__global__ __launch_bounds__(256)
void head2(const float* __restrict__ y, const float* __restrict__ Wo,
           const float* __restrict__ bo, float* __restrict__ out) {
    __shared__ float red[256];
    const int b = blockIdx.x;
    const int tid = threadIdx.x;
    float s = 0.f;
    for (int u = tid; u < U_; u += 256) s += y[(size_t)b * U_ + u] * Wo[u];
    red[tid] = s;
    __syncthreads();
    for (int off = 128; off > 0; off >>= 1) {
        if (tid < off) red[tid] += red[tid + off];
        __syncthreads();
    }
    if (tid == 0) out[b] = 1.f / (1.f + __expf(-(red[0] + bo[0])));
}

extern "C" void kernel_launch(void* const* d_in, const int* in_sizes, int n_in,
                              void* d_out, int out_size, void* d_ws, size_t ws_size,
                              hipStream_t stream) {
    const int*   tokens = (const int*)  d_in[0];
    const float* emb    = (const float*)d_in[1];
    const float* W0     = (const float*)d_in[2];
    const float* U0     = (const float*)d_in[3];
    const float* b0     = (const float*)d_in[4];
    const float* W1     = (const float*)d_in[5];
    const float* U1     = (const float*)d_in[6];
    const float* b1     = (const float*)d_in[7];
    const float* Wd     = (const float*)d_in[8];
    const float* bd     = (const float*)d_in[9];
    const float* Wo     = (const float*)d_in[10];
    const float* bo     = (const float*)d_in[11];

    // ws layout (bytes); total ~32 MB
    char* base = (char*)d_ws;
    unsigned char* h0a = (unsigned char*)(base + 0);         // 256 KB (fp8 frag128)
    unsigned char* h1a = (unsigned char*)(base + 262144);    // 256 KB
    float*         c0  = (float*)        (base + 524288);    // 1 MB
    float*         c1  = (float*)        (base + 1572864);   // 1 MB
    unsigned char* h0b = (unsigned char*)(base + 2621440);   // 256 KB
    unsigned char* h1b = (unsigned char*)(base + 2883584);   // 256 KB
    unsigned char* Xp  = (unsigned char*)(base + 3145728);   // 1.25 MB
    float*         yb  = (float*)        (base + 3145728);   // overlays Xp (dead by head)
    unsigned char* W0p = (unsigned char*)(base + 4456448);   // 512 KB (fp4)
    unsigned char* U0p = (unsigned char*)(base + 4980736);   // 8 MB (fp4)
    unsigned char* W1p = (unsigned char*)(base + 13369344);  // 8 MB (fp4)
    unsigned char* U1p = (unsigned char*)(base + 21757952);  // 8 MB (fp4)
    unsigned char* Wdp = (unsigned char*)(base + 30146560);  // 2 MB (fp4)

    // zero h0a, h1a, c0, c1 (contiguous 2.56 MB)
    hipMemsetAsync(d_ws, 0, 2621440, stream);

    embed_pack<<<(T_ * 8 * 64 * 4 + 255) / 256, 256, 0, stream>>>(tokens, emb, Xp);
    pack_all<<<6784, 256, 0, stream>>>(W0, U0, W1, U1, Wd,
                                       W0p, U0p, W1p, U1p, Wdp);

    // prologue: L0(0): x(0) + h0a(=0) -> h0b
    lstm_l0_first<<<256, 512, 0, stream>>>(Xp, W0p, U0p, b0, c0, h0a, h0b);

    // fused phases: phase k = { L1(k), L0(k+1) }
    for (int k = 0; k < T_; ++k) {
        const unsigned char* h0cur  = (k & 1) ? h0a : h0b;
        unsigned char*       h0next = (k & 1) ? h0b : h0a;   // written for k+1
        const unsigned char* h1in   = (k & 1) ? h1b : h1a;
        unsigned char*       h1out  = (k & 1) ? h1a : h1b;
        lstm_phase<<<256, 512, 0, stream>>>(Xp, W0p, U0p, W1p, U1p,
                                            b0, b1, c0, c1,
                                            h0cur, h0next, h1in, h1out, k);
    }
    // h1(79): 79 odd -> h1a
    head_mfma<<<256, 256, 0, stream>>>(h1a, Wdp, bd, yb);
    head2<<<B_, 256, 0, stream>>>(yb, Wo, bo, (float*)d_out);
}

// Round 17
// 1150.714 us; speedup vs baseline: 1.8001x; 1.0129x over previous
//
#include <hip/hip_runtime.h>
#include <hip/hip_bf16.h>
#include <hip/hip_fp8.h>
#include <cstdint>

#define B_   128
#define T_   80
#define E_   100
#define U_   2048
#define G4_  8192

// scales: A-side (x,h) fp8 x16; B-side (weights) fp4 x64; acc * 1/1024
#define SA_    16.0f
#define SB4_   64.0f
#define INV_S_ (1.0f / 1024.0f)
#define SCL1_  0x7F7F7F7F   // E8M0 = 127 -> 2^0 per 32-block (x4 packed)

typedef __attribute__((ext_vector_type(4))) float f32x4;
typedef __attribute__((ext_vector_type(8))) int   i32x8;
typedef __attribute__((ext_vector_type(4))) int   i32x4;

__device__ __forceinline__ unsigned char f2fp8(float x) {
    __hip_fp8_e4m3 q(x);
    return q.__x;
}

// fp4 e2m1 quantize (round to nearest): values {0,.5,1,1.5,2,3,4,6}
__device__ __forceinline__ unsigned int q4(float x) {
    float a = fabsf(x);
    unsigned int s = (x < 0.f) ? 8u : 0u;
    unsigned int c = a < 0.25f ? 0u : a < 0.75f ? 1u : a < 1.25f ? 2u :
                     a < 1.75f ? 3u : a < 2.5f  ? 4u : a < 3.5f  ? 5u :
                     a < 5.0f  ? 6u : 7u;
    return s | c;
}

// ---------------- embedding -> fp8 A-frag128 X: 1 window of K=128 -----------
__global__ __launch_bounds__(256)
void embed_pack(const int* __restrict__ tokens, const float* __restrict__ emb,
                unsigned char* __restrict__ Xp) {
    int gtid = blockIdx.x * 256 + threadIdx.x;   // one 8-byte chunk each
    if (gtid >= T_ * 8 * 64 * 4) return;
    int eb   = gtid & 3;
    int lane = (gtid >> 2) & 63;
    int mtg  = (gtid >> 8) & 7;
    int t    = gtid >> 11;
    int row  = (mtg >> 2) * 64 + (mtg & 3) * 16 + (lane & 15);
    const float* erow = emb + (size_t)tokens[row * T_ + t] * E_;
    unsigned char v[8];
#pragma unroll
    for (int j = 0; j < 8; ++j) {
        int k = (lane >> 4) * 32 + eb * 8 + j;
        v[j] = (k < E_) ? f2fp8(SA_ * erow[k]) : 0;
    }
    unsigned char* dst = Xp + ((size_t)(t * 8 + mtg)) * 2048 + lane * 32 + eb * 8;
    *reinterpret_cast<uint2*>(dst) = *reinterpret_cast<const uint2*>(v);
}

// ---------------- fused fp4 pack: coalesced row-reads, conflict-free emit ---
// Block = (matrix, window Wm, kg quarter, col-group of 256). Stage [32k][256c]
// fp32 with full-row wave loads (1 KB/instr), emit fragments from LDS.
// blocks: U0 [0,2048) | W1 [2048,4096) | U1 [4096,6144) |
//         W0 [6144,6272) (NW=1) | Wd [6272,6784) (NG=1, 8 colgroups)
__global__ __launch_bounds__(256)
void pack_all(const float* __restrict__ W0, const float* __restrict__ U0,
              const float* __restrict__ W1, const float* __restrict__ U1,
              const float* __restrict__ Wd,
              unsigned char* __restrict__ W0p, unsigned char* __restrict__ U0p,
              unsigned char* __restrict__ W1p, unsigned char* __restrict__ U1p,
              unsigned char* __restrict__ Wdp) {
    __shared__ float4 st4[32][65];   // [k-row][64 float4 cols + pad]
    const float* stf = reinterpret_cast<const float*>(&st4[0][0]);
    const int tid = threadIdx.x;
    int blk = blockIdx.x;
    const float* W; int K, Ncols, NG, NW; unsigned char* out; int lb;
    if (blk < 2048)      { W = U0; K = U_; Ncols = G4_; NG = 4; NW = 16; out = U0p; lb = blk; }
    else if (blk < 4096) { W = W1; K = U_; Ncols = G4_; NG = 4; NW = 16; out = W1p; lb = blk - 2048; }
    else if (blk < 6144) { W = U1; K = U_; Ncols = G4_; NG = 4; NW = 16; out = U1p; lb = blk - 4096; }
    else if (blk < 6272) { W = W0; K = E_; Ncols = G4_; NG = 4; NW = 1;  out = W0p; lb = blk - 6144; }
    else                 { W = Wd; K = U_; Ncols = U_;  NG = 1; NW = 16; out = Wdp; lb = blk - 6272; }

    int Wm, kg, cg;
    if (NW == 1) { Wm = 0;        kg = lb & 3;         cg = lb >> 2; }
    else         { Wm = lb & 15;  kg = (lb >> 4) & 3;  cg = lb >> 6; }
    int g, utb;
    if (NG == 4) { g = cg >> 3; utb = (cg & 7) * 16; }
    else         { g = 0;       utb = cg * 16; }
    const int cb = cg * 256;     // absolute col base (includes gate offset)

    // stage: 8 passes; each wave loads one full 1 KB row (fully coalesced)
    {
        const int c4 = tid & 63;
        const int r0 = tid >> 6;
#pragma unroll
        for (int p = 0; p < 8; ++p) {
            const int r = p * 4 + r0;
            const int k = Wm * 128 + kg * 32 + r;
            float4 v = make_float4(0.f, 0.f, 0.f, 0.f);
            if (k < K)
                v = *reinterpret_cast<const float4*>(W + (size_t)k * Ncols + cb + c4 * 4);
            st4[r][c4] = v;
        }
    }
    __syncthreads();

    // emit: thread = (ut_local, cl); float col = tid; rows 2b, 2b+1
    const int ut_l = tid >> 4;
    const int cl   = tid & 15;
    unsigned char v[16];
#pragma unroll
    for (int b = 0; b < 16; ++b) {
        float v0 = stf[((2 * b)     * 65 + (tid >> 2)) * 4 + (tid & 3)];
        float v1 = stf[((2 * b + 1) * 65 + (tid >> 2)) * 4 + (tid & 3)];
        v[b] = (unsigned char)(q4(SB4_ * v0) | (q4(SB4_ * v1) << 4));
    }
    const int ut = utb + ut_l;
    unsigned char* dst = out + (((size_t)(ut * NW + Wm)) * NG + g) * 1024 + (kg * 16 + cl) * 16;
    *reinterpret_cast<uint4*>(dst) = *reinterpret_cast<const uint4*>(v);
}

// ---------------- window-set load / MFMA-set helpers ------------------------
template<int NW0, int NW1>
__device__ __forceinline__ void ld_set(
    const unsigned char* __restrict__ a0, const unsigned char* __restrict__ a1,
    const unsigned char* __restrict__ b0, const unsigned char* __restrict__ b1,
    int w, i32x8 (&A)[4], i32x4 (&Bv)[4])
{
    if (w < NW0) {
#pragma unroll
        for (int mt = 0; mt < 4; ++mt)
            A[mt] = *reinterpret_cast<const i32x8*>(a0 + (size_t)(mt * NW0 + w) * 2048);
#pragma unroll
        for (int g = 0; g < 4; ++g)
            Bv[g] = *reinterpret_cast<const i32x4*>(b0 + (size_t)(w * 4 + g) * 1024);
    } else {
        int ww = w - NW0;
#pragma unroll
        for (int mt = 0; mt < 4; ++mt)
            A[mt] = *reinterpret_cast<const i32x8*>(a1 + (size_t)(mt * NW1 + ww) * 2048);
#pragma unroll
        for (int g = 0; g < 4; ++g)
            Bv[g] = *reinterpret_cast<const i32x4*>(b1 + (size_t)(ww * 4 + g) * 1024);
    }
}

__device__ __forceinline__ void mfma_set(f32x4 (&acc)[4][4], i32x8 (&A)[4], i32x4 (&Bv)[4]) {
    __builtin_amdgcn_s_setprio(1);
#pragma unroll
    for (int g = 0; g < 4; ++g) {
        i32x8 bf = {Bv[g][0], Bv[g][1], Bv[g][2], Bv[g][3], 0, 0, 0, 0};
#pragma unroll
        for (int mt = 0; mt < 4; ++mt)
            acc[g][mt] = __builtin_amdgcn_mfma_scale_f32_16x16x128_f8f6f4(
                A[mt], bf, acc[g][mt], 0, 4, 0, SCL1_, 0, SCL1_);
    }
    __builtin_amdgcn_s_setprio(0);
}

// ---------------- epilogue: 8-way kq reduction + cell update + packed h -----
__device__ __forceinline__ void epilogue(
    f32x4 (&acc)[4][4], const float* __restrict__ bias,
    float* __restrict__ c, unsigned char* __restrict__ h_out,
    float (*zs)[2][64][17], int ut, int mh, int tid, int lane, int kq)
{
    const int lr = tid >> 3;          // 0..63
    const int u0 = (tid & 7) * 2;     // 0,2,..,14
    float zg2[4][2];
#pragma unroll
    for (int rnd = 0; rnd < 2; ++rnd) {
        __syncthreads();
#pragma unroll
        for (int gg = 0; gg < 2; ++gg) {
            const int g = rnd * 2 + gg;
#pragma unroll
            for (int mt = 0; mt < 4; ++mt)
#pragma unroll
                for (int r = 0; r < 4; ++r)
                    zs[kq][gg][mt * 16 + (lane >> 4) * 4 + r][lane & 15] = acc[g][mt][r];
        }
        __syncthreads();
#pragma unroll
        for (int gg = 0; gg < 2; ++gg) {
            float s0 = 0.f, s1 = 0.f;
#pragma unroll
            for (int w8 = 0; w8 < 8; ++w8) {
                s0 += zs[w8][gg][lr][u0];
                s1 += zs[w8][gg][lr][u0 + 1];
            }
            zg2[rnd * 2 + gg][0] = s0;
            zg2[rnd * 2 + gg][1] = s1;
        }
    }

    const int grow = mh * 64 + lr;
    const int unit = ut * 16 + u0;
    const float2 bi  = *reinterpret_cast<const float2*>(&bias[unit]);
    const float2 bfv = *reinterpret_cast<const float2*>(&bias[U_ + unit]);
    const float2 bgv = *reinterpret_cast<const float2*>(&bias[2 * U_ + unit]);
    const float2 bov = *reinterpret_cast<const float2*>(&bias[3 * U_ + unit]);
    float2 cv = *reinterpret_cast<float2*>(&c[(size_t)grow * U_ + unit]);

    float cn[2];
    unsigned char hv[2];
#pragma unroll
    for (int e = 0; e < 2; ++e) {
        float zi = zg2[0][e] * INV_S_ + (e ? bi.y : bi.x);
        float zf = zg2[1][e] * INV_S_ + (e ? bfv.y : bfv.x);
        float zg = zg2[2][e] * INV_S_ + (e ? bgv.y : bgv.x);
        float zo = zg2[3][e] * INV_S_ + (e ? bov.y : bov.x);
        float si = 1.f / (1.f + __expf(-zi));
        float sf = 1.f / (1.f + __expf(-zf));
        float so = 1.f / (1.f + __expf(-zo));
        float tg = tanhf(zg);
        float cc = sf * (e ? cv.y : cv.x) + si * tg;
        cn[e] = cc;
        hv[e] = f2fp8(SA_ * so * tanhf(cc));
    }
    *reinterpret_cast<float2*>(&c[(size_t)grow * U_ + unit]) = make_float2(cn[0], cn[1]);

    const int mt = lr >> 4;
    const int cl = lr & 15;
    const int Wh = unit >> 7;
    const int lg = (unit >> 5) & 3;
    const int e0 = unit & 31;            // even
    size_t fr = (size_t)(mh * 4 + mt) * 16 + Wh;
    uchar2 hv2; hv2.x = hv[0]; hv2.y = hv[1];
    *reinterpret_cast<uchar2*>(&h_out[fr * 2048 + (lg * 16 + cl) * 32 + e0]) = hv2;
}

// ---------------- prologue: L0(0) only (grid 256, XCD-swizzled) -------------
__global__ __launch_bounds__(512)
void lstm_l0_first(const unsigned char* __restrict__ Xp,
                   const unsigned char* __restrict__ W0p,
                   const unsigned char* __restrict__ U0p,
                   const float* __restrict__ b0,
                   float* __restrict__ c0,
                   const unsigned char* __restrict__ h0zero,
                   unsigned char* __restrict__ h0out) {
    __shared__ float zs[8][2][64][17];
    const int tid  = threadIdx.x;
    const int lane = tid & 63;
    const int kq   = tid >> 6;
    const int b    = blockIdx.x;
    const int s    = b >> 3;
    const int ut   = (b & 7) * 16 + (s >> 1);
    const int mh   = s & 1;

    const unsigned char* a0 = Xp     + ((size_t)(mh * 4) * 1)  * 2048 + lane * 32;
    const unsigned char* a1 = h0zero + ((size_t)(mh * 4) * 16) * 2048 + lane * 32;
    const unsigned char* p0 = W0p + ((size_t)(ut * 1)  * 4) * 1024 + lane * 16;
    const unsigned char* p1 = U0p + ((size_t)(ut * 16) * 4) * 1024 + lane * 16;

    f32x4 acc[4][4];
#pragma unroll
    for (int g = 0; g < 4; ++g)
#pragma unroll
        for (int mt = 0; mt < 4; ++mt) acc[g][mt] = f32x4{0.f, 0.f, 0.f, 0.f};

    i32x8 A0s[4], A1s[4], A2s[4];
    i32x4 B0s[4], B1s[4], B2s[4];
    ld_set<1, 16>(a0, a1, p0, p1, kq, A0s, B0s);
    ld_set<1, 16>(a0, a1, p0, p1, kq + 8, A1s, B1s);
    const bool tail = (kq + 16 < 17);
    if (tail) ld_set<1, 16>(a0, a1, p0, p1, kq + 16, A2s, B2s);
    mfma_set(acc, A0s, B0s);
    mfma_set(acc, A1s, B1s);
    if (tail) mfma_set(acc, A2s, B2s);

    epilogue(acc, b0, c0, h0out, zs, ut, mh, tid, lane, kq);
}

// ---------------- fused phase k: L1(k) sweep, L0 prefetch, epilogues --------
__global__ __launch_bounds__(512)
void lstm_phase(const unsigned char* __restrict__ Xp,
                const unsigned char* __restrict__ W0p,
                const unsigned char* __restrict__ U0p,
                const unsigned char* __restrict__ W1p,
                const unsigned char* __restrict__ U1p,
                const float* __restrict__ b0,
                const float* __restrict__ b1,
                float* __restrict__ c0, float* __restrict__ c1,
                const unsigned char* __restrict__ h0cur,
                unsigned char* __restrict__ h0next,
                const unsigned char* __restrict__ h1in,
                unsigned char* __restrict__ h1out,
                int k) {
    __shared__ float zs[8][2][64][17];
    const int tid  = threadIdx.x;
    const int lane = tid & 63;
    const int kq   = tid >> 6;
    const int b    = blockIdx.x;
    const int s    = b >> 3;
    const int ut   = (b & 7) * 16 + (s >> 1);   // xcd owns 16 consecutive ut
    const int mh   = s & 1;
    const bool hasL0 = (k + 1 < T_);

    // L1 pointers
    const unsigned char* a0 = h0cur + ((size_t)(mh * 4) * 16) * 2048 + lane * 32;
    const unsigned char* a1 = h1in  + ((size_t)(mh * 4) * 16) * 2048 + lane * 32;
    const unsigned char* p0 = W1p + ((size_t)(ut * 16) * 4) * 1024 + lane * 16;
    const unsigned char* p1 = U1p + ((size_t)(ut * 16) * 4) * 1024 + lane * 16;
    // L0 pointers
    const unsigned char* l0a0 = Xp + (size_t)(k + 1) * 8 * 2048
                                   + ((size_t)(mh * 4) * 1) * 2048 + lane * 32;
    const unsigned char* l0a1 = h0cur + ((size_t)(mh * 4) * 16) * 2048 + lane * 32;
    const unsigned char* l0b0 = W0p + ((size_t)(ut * 1)  * 4) * 1024 + lane * 16;
    const unsigned char* l0b1 = U0p + ((size_t)(ut * 16) * 4) * 1024 + lane * 16;

    f32x4 acc[4][4];
#pragma unroll
    for (int g = 0; g < 4; ++g)
#pragma unroll
        for (int mt = 0; mt < 4; ++mt) acc[g][mt] = f32x4{0.f, 0.f, 0.f, 0.f};

    // L1 sweep: depth-3 static, windows kq, kq+8, kq+16, kq+24 (NW=32)
    {
        i32x8 A0s[4], A1s[4], A2s[4];
        i32x4 B0s[4], B1s[4], B2s[4];
        ld_set<16, 16>(a0, a1, p0, p1, kq,      A0s, B0s);
        ld_set<16, 16>(a0, a1, p0, p1, kq + 8,  A1s, B1s);
        ld_set<16, 16>(a0, a1, p0, p1, kq + 16, A2s, B2s);
        mfma_set(acc, A0s, B0s);
        ld_set<16, 16>(a0, a1, p0, p1, kq + 24, A0s, B0s);
        mfma_set(acc, A1s, B1s);
        mfma_set(acc, A2s, B2s);
        mfma_set(acc, A0s, B0s);
    }

    // prefetch L0 window set 0 — its latency hides under L1's epilogue
    i32x8 PA[4]; i32x4 PB[4];
    if (hasL0) ld_set<1, 16>(l0a0, l0a1, l0b0, l0b1, kq, PA, PB);

    // L1 epilogue (4 barriers)
    epilogue(acc, b1, c1, h1out, zs, ut, mh, tid, lane, kq);

    // L0 sweep + epilogue
    if (hasL0) {
#pragma unroll
        for (int g = 0; g < 4; ++g)
#pragma unroll
            for (int mt = 0; mt < 4; ++mt) acc[g][mt] = f32x4{0.f, 0.f, 0.f, 0.f};

        i32x8 A1s[4], A2s[4];
        i32x4 B1s[4], B2s[4];
        ld_set<1, 16>(l0a0, l0a1, l0b0, l0b1, kq + 8, A1s, B1s);
        const bool tail = (kq + 16 < 17);
        if (tail) ld_set<1, 16>(l0a0, l0a1, l0b0, l0b1, kq + 16, A2s, B2s);
        mfma_set(acc, PA, PB);
        mfma_set(acc, A1s, B1s);
        if (tail) mfma_set(acc, A2s, B2s);

        epilogue(acc, b0, c0, h0next, zs, ut, mh, tid, lane, kq);
    }
}

// ---------------- head: y = relu((h1 @ Wd)/1024 + bd); fp8 x fp4 ------------
__global__ __launch_bounds__(256)
void head_mfma(const unsigned char* __restrict__ h1p,
               const unsigned char* __restrict__ Wdp,
               const float* __restrict__ bd, float* __restrict__ y) {
    const int lane = threadIdx.x & 63;
    const int w    = threadIdx.x >> 6;  // k-split wave
    const int ut   = blockIdx.x & 127;
    const int mh   = blockIdx.x >> 7;

    const unsigned char* ap = h1p + ((size_t)(mh * 4) * 16) * 2048 + lane * 32;
    const unsigned char* wp = Wdp + ((size_t)(ut * 16)) * 1024 + lane * 16;

    f32x4 acc[4];
#pragma unroll
    for (int mt = 0; mt < 4; ++mt) acc[mt] = f32x4{0.f, 0.f, 0.f, 0.f};

#pragma unroll
    for (int wi = 0; wi < 4; ++wi) {
        const int W = w + wi * 4;
        i32x4 bq = *reinterpret_cast<const i32x4*>(wp + (size_t)W * 1024);
        i32x8 bf = {bq[0], bq[1], bq[2], bq[3], 0, 0, 0, 0};
#pragma unroll
        for (int mt = 0; mt < 4; ++mt) {
            i32x8 a = *reinterpret_cast<const i32x8*>(ap + (size_t)(mt * 16 + W) * 2048);
            acc[mt] = __builtin_amdgcn_mfma_scale_f32_16x16x128_f8f6f4(
                a, bf, acc[mt], 0, 4, 0, SCL1_, 0, SCL1_);
        }
    }

    __shared__ float zs[4][64][17];
#pragma unroll
    for (int mt = 0; mt < 4; ++mt)
#pragma unroll
        for (int r = 0; r < 4; ++r)
            zs[w][mt * 16 + (lane >> 4) * 4 + r][lane & 15] = acc[mt][r];
    __syncthreads();

    const int tid = threadIdx.x;
    const int lr  = tid >> 2;
    const int u4  = (tid & 3) * 4;
    const int grow = mh * 64 + lr;
    const int gu   = ut * 16 + u4;

    float4 r;
    float* rr = &r.x;
#pragma unroll
    for (int e = 0; e < 4; ++e) {
        float v = (zs[0][lr][u4 + e] + zs[1][lr][u4 + e] +
                   zs[2][lr][u4 + e] + zs[3][lr][u4 + e]) * INV_S_ + bd[gu + e];
        rr[e] = v > 0.f ? v : 0.f;
    }
    *reinterpret_cast<float4*>(&y[(size_t)grow * U_ + gu]) = r;
}

// ---------------- out[b] = sigmoid(y[b,:] @ Wo + bo) ----------------
__global__ __launch_bounds__(256)
void head2(const float* __restrict__ y, const float* __restrict__ Wo,
           const float* __restrict__ bo, float* __restrict__ out) {
    __shared__ float red[256];
    const int b = blockIdx.x;
    const int tid = threadIdx.x;
    float s = 0.f;
    for (int u = tid; u < U_; u += 256) s += y[(size_t)b * U_ + u] * Wo[u];
    red[tid] = s;
    __syncthreads();
    for (int off = 128; off > 0; off >>= 1) {
        if (tid < off) red[tid] += red[tid + off];
        __syncthreads();
    }
    if (tid == 0) out[b] = 1.f / (1.f + __expf(-(red[0] + bo[0])));
}

extern "C" void kernel_launch(void* const* d_in, const int* in_sizes, int n_in,
                              void* d_out, int out_size, void* d_ws, size_t ws_size,
                              hipStream_t stream) {
    const int*   tokens = (const int*)  d_in[0];
    const float* emb    = (const float*)d_in[1];
    const float* W0     = (const float*)d_in[2];
    const float* U0     = (const float*)d_in[3];
    const float* b0     = (const float*)d_in[4];
    const float* W1     = (const float*)d_in[5];
    const float* U1     = (const float*)d_in[6];
    const float* b1     = (const float*)d_in[7];
    const float* Wd     = (const float*)d_in[8];
    const float* bd     = (const float*)d_in[9];
    const float* Wo     = (const float*)d_in[10];
    const float* bo     = (const float*)d_in[11];

    // ws layout (bytes); total ~32 MB
    char* base = (char*)d_ws;
    unsigned char* h0a = (unsigned char*)(base + 0);         // 256 KB (fp8 frag128)
    unsigned char* h1a = (unsigned char*)(base + 262144);    // 256 KB
    float*         c0  = (float*)        (base + 524288);    // 1 MB
    float*         c1  = (float*)        (base + 1572864);   // 1 MB
    unsigned char* h0b = (unsigned char*)(base + 2621440);   // 256 KB
    unsigned char* h1b = (unsigned char*)(base + 2883584);   // 256 KB
    unsigned char* Xp  = (unsigned char*)(base + 3145728);   // 1.25 MB
    float*         yb  = (float*)        (base + 3145728);   // overlays Xp (dead by head)
    unsigned char* W0p = (unsigned char*)(base + 4456448);   // 512 KB (fp4)
    unsigned char* U0p = (unsigned char*)(base + 4980736);   // 8 MB (fp4)
    unsigned char* W1p = (unsigned char*)(base + 13369344);  // 8 MB (fp4)
    unsigned char* U1p = (unsigned char*)(base + 21757952);  // 8 MB (fp4)
    unsigned char* Wdp = (unsigned char*)(base + 30146560);  // 2 MB (fp4)

    // zero h0a, h1a, c0, c1 (contiguous 2.56 MB)
    hipMemsetAsync(d_ws, 0, 2621440, stream);

    embed_pack<<<(T_ * 8 * 64 * 4 + 255) / 256, 256, 0, stream>>>(tokens, emb, Xp);
    pack_all<<<6784, 256, 0, stream>>>(W0, U0, W1, U1, Wd,
                                       W0p, U0p, W1p, U1p, Wdp);

    // prologue: L0(0): x(0) + h0a(=0) -> h0b
    lstm_l0_first<<<256, 512, 0, stream>>>(Xp, W0p, U0p, b0, c0, h0a, h0b);

    // fused phases: phase k = { L1(k), L0(k+1) }
    for (int k = 0; k < T_; ++k) {
        const unsigned char* h0cur  = (k & 1) ? h0a : h0b;
        unsigned char*       h0next = (k & 1) ? h0b : h0a;   // written for k+1
        const unsigned char* h1in   = (k & 1) ? h1b : h1a;
        unsigned char*       h1out  = (k & 1) ? h1a : h1b;
        lstm_phase<<<256, 512, 0, stream>>>(Xp, W0p, U0p, W1p, U1p,
                                            b0, b1, c0, c1,
                                            h0cur, h0next, h1in, h1out, k);
    }
    // h1(79): 79 odd -> h1a
    head_mfma<<<256, 256, 0, stream>>>(h1a, Wdp, bd, yb);
    head2<<<B_, 256, 0, stream>>>(yb, Wo, bo, (float*)d_out);
}

// Round 18
// 1094.106 us; speedup vs baseline: 1.8932x; 1.0517x over previous
//
#include <hip/hip_runtime.h>
#include <hip/hip_bf16.h>
#include <hip/hip_fp8.h>
#include <cstdint>

#define B_   128
#define T_   80
#define E_   100
#define U_   2048
#define G4_  8192

// scales: A-side (x,h) fp8 x16; B-side (weights) fp4 x64; acc * 1/1024
#define SA_    16.0f
#define SB4_   64.0f
#define INV_S_ (1.0f / 1024.0f)
#define SCL1_  0x7F7F7F7F   // E8M0 = 127 -> 2^0 per 32-block (x4 packed)

typedef __attribute__((ext_vector_type(4))) float f32x4;
typedef __attribute__((ext_vector_type(8))) int   i32x8;
typedef __attribute__((ext_vector_type(4))) int   i32x4;

__device__ __forceinline__ unsigned char f2fp8(float x) {
    __hip_fp8_e4m3 q(x);
    return q.__x;
}

// fp4 e2m1 quantize (round to nearest): values {0,.5,1,1.5,2,3,4,6}
__device__ __forceinline__ unsigned int q4(float x) {
    float a = fabsf(x);
    unsigned int s = (x < 0.f) ? 8u : 0u;
    unsigned int c = a < 0.25f ? 0u : a < 0.75f ? 1u : a < 1.25f ? 2u :
                     a < 1.75f ? 3u : a < 2.5f  ? 4u : a < 3.5f  ? 5u :
                     a < 5.0f  ? 6u : 7u;
    return s | c;
}

// ---------------- embedding -> fp8 A-frag128 X: 1 window of K=128 -----------
__global__ __launch_bounds__(256)
void embed_pack(const int* __restrict__ tokens, const float* __restrict__ emb,
                unsigned char* __restrict__ Xp) {
    int gtid = blockIdx.x * 256 + threadIdx.x;   // one 8-byte chunk each
    if (gtid >= T_ * 8 * 64 * 4) return;
    int eb   = gtid & 3;
    int lane = (gtid >> 2) & 63;
    int mtg  = (gtid >> 8) & 7;
    int t    = gtid >> 11;
    int row  = (mtg >> 2) * 64 + (mtg & 3) * 16 + (lane & 15);
    const float* erow = emb + (size_t)tokens[row * T_ + t] * E_;
    unsigned char v[8];
#pragma unroll
    for (int j = 0; j < 8; ++j) {
        int k = (lane >> 4) * 32 + eb * 8 + j;
        v[j] = (k < E_) ? f2fp8(SA_ * erow[k]) : 0;
    }
    unsigned char* dst = Xp + ((size_t)(t * 8 + mtg)) * 2048 + lane * 32 + eb * 8;
    *reinterpret_cast<uint2*>(dst) = *reinterpret_cast<const uint2*>(v);
}

// ---------------- fused fp4 pack: coalesced row-reads, conflict-free emit ---
__global__ __launch_bounds__(256)
void pack_all(const float* __restrict__ W0, const float* __restrict__ U0,
              const float* __restrict__ W1, const float* __restrict__ U1,
              const float* __restrict__ Wd,
              unsigned char* __restrict__ W0p, unsigned char* __restrict__ U0p,
              unsigned char* __restrict__ W1p, unsigned char* __restrict__ U1p,
              unsigned char* __restrict__ Wdp) {
    __shared__ float4 st4[32][65];   // [k-row][64 float4 cols + pad]
    const float* stf = reinterpret_cast<const float*>(&st4[0][0]);
    const int tid = threadIdx.x;
    int blk = blockIdx.x;
    const float* W; int K, Ncols, NG, NW; unsigned char* out; int lb;
    if (blk < 2048)      { W = U0; K = U_; Ncols = G4_; NG = 4; NW = 16; out = U0p; lb = blk; }
    else if (blk < 4096) { W = W1; K = U_; Ncols = G4_; NG = 4; NW = 16; out = W1p; lb = blk - 2048; }
    else if (blk < 6144) { W = U1; K = U_; Ncols = G4_; NG = 4; NW = 16; out = U1p; lb = blk - 4096; }
    else if (blk < 6272) { W = W0; K = E_; Ncols = G4_; NG = 4; NW = 1;  out = W0p; lb = blk - 6144; }
    else                 { W = Wd; K = U_; Ncols = U_;  NG = 1; NW = 16; out = Wdp; lb = blk - 6272; }

    int Wm, kg, cg;
    if (NW == 1) { Wm = 0;        kg = lb & 3;         cg = lb >> 2; }
    else         { Wm = lb & 15;  kg = (lb >> 4) & 3;  cg = lb >> 6; }
    int g, utb;
    if (NG == 4) { g = cg >> 3; utb = (cg & 7) * 16; }
    else         { g = 0;       utb = cg * 16; }
    const int cb = cg * 256;     // absolute col base (includes gate offset)

    {
        const int c4 = tid & 63;
        const int r0 = tid >> 6;
#pragma unroll
        for (int p = 0; p < 8; ++p) {
            const int r = p * 4 + r0;
            const int k = Wm * 128 + kg * 32 + r;
            float4 v = make_float4(0.f, 0.f, 0.f, 0.f);
            if (k < K)
                v = *reinterpret_cast<const float4*>(W + (size_t)k * Ncols + cb + c4 * 4);
            st4[r][c4] = v;
        }
    }
    __syncthreads();

    const int ut_l = tid >> 4;
    const int cl   = tid & 15;
    unsigned char v[16];
#pragma unroll
    for (int b = 0; b < 16; ++b) {
        float v0 = stf[((2 * b)     * 65 + (tid >> 2)) * 4 + (tid & 3)];
        float v1 = stf[((2 * b + 1) * 65 + (tid >> 2)) * 4 + (tid & 3)];
        v[b] = (unsigned char)(q4(SB4_ * v0) | (q4(SB4_ * v1) << 4));
    }
    const int ut = utb + ut_l;
    unsigned char* dst = out + (((size_t)(ut * NW + Wm)) * NG + g) * 1024 + (kg * 16 + cl) * 16;
    *reinterpret_cast<uint4*>(dst) = *reinterpret_cast<const uint4*>(v);
}

// ---------------- window-set load / MFMA-set helpers ------------------------
template<int NW0, int NW1>
__device__ __forceinline__ void ld_set(
    const unsigned char* __restrict__ a0, const unsigned char* __restrict__ a1,
    const unsigned char* __restrict__ b0, const unsigned char* __restrict__ b1,
    int w, i32x8 (&A)[4], i32x4 (&Bv)[4])
{
    if (w < NW0) {
#pragma unroll
        for (int mt = 0; mt < 4; ++mt)
            A[mt] = *reinterpret_cast<const i32x8*>(a0 + (size_t)(mt * NW0 + w) * 2048);
#pragma unroll
        for (int g = 0; g < 4; ++g)
            Bv[g] = *reinterpret_cast<const i32x4*>(b0 + (size_t)(w * 4 + g) * 1024);
    } else {
        int ww = w - NW0;
#pragma unroll
        for (int mt = 0; mt < 4; ++mt)
            A[mt] = *reinterpret_cast<const i32x8*>(a1 + (size_t)(mt * NW1 + ww) * 2048);
#pragma unroll
        for (int g = 0; g < 4; ++g)
            Bv[g] = *reinterpret_cast<const i32x4*>(b1 + (size_t)(ww * 4 + g) * 1024);
    }
}

__device__ __forceinline__ void ld_A(const unsigned char* __restrict__ a,
                                     int stride_nw, int w, i32x8 (&A)[4]) {
#pragma unroll
    for (int mt = 0; mt < 4; ++mt)
        A[mt] = *reinterpret_cast<const i32x8*>(a + (size_t)(mt * stride_nw + w) * 2048);
}

__device__ __forceinline__ void ld_B(const unsigned char* __restrict__ b,
                                     int w, i32x4 (&Bv)[4]) {
#pragma unroll
    for (int g = 0; g < 4; ++g)
        Bv[g] = *reinterpret_cast<const i32x4*>(b + (size_t)(w * 4 + g) * 1024);
}

__device__ __forceinline__ void mfma_set(f32x4 (&acc)[4][4], i32x8 (&A)[4], i32x4 (&Bv)[4]) {
    __builtin_amdgcn_s_setprio(1);
#pragma unroll
    for (int g = 0; g < 4; ++g) {
        i32x8 bf = {Bv[g][0], Bv[g][1], Bv[g][2], Bv[g][3], 0, 0, 0, 0};
#pragma unroll
        for (int mt = 0; mt < 4; ++mt)
            acc[g][mt] = __builtin_amdgcn_mfma_scale_f32_16x16x128_f8f6f4(
                A[mt], bf, acc[g][mt], 0, 4, 0, SCL1_, 0, SCL1_);
    }
    __builtin_amdgcn_s_setprio(0);
}

// ---------------- epilogue: 8-way kq reduction + cell update + packed h -----
__device__ __forceinline__ void epilogue(
    f32x4 (&acc)[4][4], const float* __restrict__ bias,
    float* __restrict__ c, unsigned char* __restrict__ h_out,
    float (*zs)[2][64][17], int ut, int mh, int tid, int lane, int kq)
{
    const int lr = tid >> 3;          // 0..63
    const int u0 = (tid & 7) * 2;     // 0,2,..,14
    float zg2[4][2];
#pragma unroll
    for (int rnd = 0; rnd < 2; ++rnd) {
        __syncthreads();
#pragma unroll
        for (int gg = 0; gg < 2; ++gg) {
            const int g = rnd * 2 + gg;
#pragma unroll
            for (int mt = 0; mt < 4; ++mt)
#pragma unroll
                for (int r = 0; r < 4; ++r)
                    zs[kq][gg][mt * 16 + (lane >> 4) * 4 + r][lane & 15] = acc[g][mt][r];
        }
        __syncthreads();
#pragma unroll
        for (int gg = 0; gg < 2; ++gg) {
            float s0 = 0.f, s1 = 0.f;
#pragma unroll
            for (int w8 = 0; w8 < 8; ++w8) {
                s0 += zs[w8][gg][lr][u0];
                s1 += zs[w8][gg][lr][u0 + 1];
            }
            zg2[rnd * 2 + gg][0] = s0;
            zg2[rnd * 2 + gg][1] = s1;
        }
    }

    const int grow = mh * 64 + lr;
    const int unit = ut * 16 + u0;
    const float2 bi  = *reinterpret_cast<const float2*>(&bias[unit]);
    const float2 bfv = *reinterpret_cast<const float2*>(&bias[U_ + unit]);
    const float2 bgv = *reinterpret_cast<const float2*>(&bias[2 * U_ + unit]);
    const float2 bov = *reinterpret_cast<const float2*>(&bias[3 * U_ + unit]);
    float2 cv = *reinterpret_cast<float2*>(&c[(size_t)grow * U_ + unit]);

    float cn[2];
    unsigned char hv[2];
#pragma unroll
    for (int e = 0; e < 2; ++e) {
        float zi = zg2[0][e] * INV_S_ + (e ? bi.y : bi.x);
        float zf = zg2[1][e] * INV_S_ + (e ? bfv.y : bfv.x);
        float zg = zg2[2][e] * INV_S_ + (e ? bgv.y : bgv.x);
        float zo = zg2[3][e] * INV_S_ + (e ? bov.y : bov.x);
        float si = 1.f / (1.f + __expf(-zi));
        float sf = 1.f / (1.f + __expf(-zf));
        float so = 1.f / (1.f + __expf(-zo));
        float tg = tanhf(zg);
        float cc = sf * (e ? cv.y : cv.x) + si * tg;
        cn[e] = cc;
        hv[e] = f2fp8(SA_ * so * tanhf(cc));
    }
    *reinterpret_cast<float2*>(&c[(size_t)grow * U_ + unit]) = make_float2(cn[0], cn[1]);

    const int mt = lr >> 4;
    const int cl = lr & 15;
    const int Wh = unit >> 7;
    const int lg = (unit >> 5) & 3;
    const int e0 = unit & 31;            // even
    size_t fr = (size_t)(mh * 4 + mt) * 16 + Wh;
    uchar2 hv2; hv2.x = hv[0]; hv2.y = hv[1];
    *reinterpret_cast<uchar2*>(&h_out[fr * 2048 + (lg * 16 + cl) * 32 + e0]) = hv2;
}

// ---------------- prologue: L0(0) only (grid 256, XCD-swizzled) -------------
__global__ __launch_bounds__(512)
void lstm_l0_first(const unsigned char* __restrict__ Xp,
                   const unsigned char* __restrict__ W0p,
                   const unsigned char* __restrict__ U0p,
                   const float* __restrict__ b0,
                   float* __restrict__ c0,
                   const unsigned char* __restrict__ h0zero,
                   unsigned char* __restrict__ h0out) {
    __shared__ float zs[8][2][64][17];
    const int tid  = threadIdx.x;
    const int lane = tid & 63;
    const int kq   = tid >> 6;
    const int b    = blockIdx.x;
    const int s    = b >> 3;
    const int ut   = (b & 7) * 16 + (s >> 1);
    const int mh   = s & 1;

    const unsigned char* a0 = Xp     + ((size_t)(mh * 4) * 1)  * 2048 + lane * 32;
    const unsigned char* a1 = h0zero + ((size_t)(mh * 4) * 16) * 2048 + lane * 32;
    const unsigned char* p0 = W0p + ((size_t)(ut * 1)  * 4) * 1024 + lane * 16;
    const unsigned char* p1 = U0p + ((size_t)(ut * 16) * 4) * 1024 + lane * 16;

    f32x4 acc[4][4];
#pragma unroll
    for (int g = 0; g < 4; ++g)
#pragma unroll
        for (int mt = 0; mt < 4; ++mt) acc[g][mt] = f32x4{0.f, 0.f, 0.f, 0.f};

    i32x8 A0s[4], A1s[4], A2s[4];
    i32x4 B0s[4], B1s[4], B2s[4];
    ld_set<1, 16>(a0, a1, p0, p1, kq, A0s, B0s);
    ld_set<1, 16>(a0, a1, p0, p1, kq + 8, A1s, B1s);
    const bool tail = (kq + 16 < 17);
    if (tail) ld_set<1, 16>(a0, a1, p0, p1, kq + 16, A2s, B2s);
    mfma_set(acc, A0s, B0s);
    mfma_set(acc, A1s, B1s);
    if (tail) mfma_set(acc, A2s, B2s);

    epilogue(acc, b0, c0, h0out, zs, ut, mh, tid, lane, kq);
}

// ---------------- fused phase k: L1(k) sweep, L0(k+1) reusing h0 regs -------
__global__ __launch_bounds__(512)
void lstm_phase(const unsigned char* __restrict__ Xp,
                const unsigned char* __restrict__ W0p,
                const unsigned char* __restrict__ U0p,
                const unsigned char* __restrict__ W1p,
                const unsigned char* __restrict__ U1p,
                const float* __restrict__ b0,
                const float* __restrict__ b1,
                float* __restrict__ c0, float* __restrict__ c1,
                const unsigned char* __restrict__ h0cur,
                unsigned char* __restrict__ h0next,
                const unsigned char* __restrict__ h1in,
                unsigned char* __restrict__ h1out,
                int k) {
    __shared__ float zs[8][2][64][17];
    const int tid  = threadIdx.x;
    const int lane = tid & 63;
    const int kq   = tid >> 6;
    const int b    = blockIdx.x;
    const int s    = b >> 3;
    const int ut   = (b & 7) * 16 + (s >> 1);   // xcd owns 16 consecutive ut
    const int mh   = s & 1;
    const bool hasL0 = (k + 1 < T_);

    // L1 operand pointers; a0 = h0cur panel (windows 0..15), a1 = h1in
    const unsigned char* a0 = h0cur + ((size_t)(mh * 4) * 16) * 2048 + lane * 32;
    const unsigned char* a1 = h1in  + ((size_t)(mh * 4) * 16) * 2048 + lane * 32;
    const unsigned char* p0 = W1p + ((size_t)(ut * 16) * 4) * 1024 + lane * 16;
    const unsigned char* p1 = U1p + ((size_t)(ut * 16) * 4) * 1024 + lane * 16;
    // L0 operand pointers
    const unsigned char* l0x  = Xp + (size_t)(k + 1) * 8 * 2048
                                   + ((size_t)(mh * 4) * 1) * 2048 + lane * 32;
    const unsigned char* l0b0 = W0p + ((size_t)(ut * 1)  * 4) * 1024 + lane * 16;
    const unsigned char* l0b1 = U0p + ((size_t)(ut * 16) * 4) * 1024 + lane * 16;

    f32x4 acc[4][4];
#pragma unroll
    for (int g = 0; g < 4; ++g)
#pragma unroll
        for (int mt = 0; mt < 4; ++mt) acc[g][mt] = f32x4{0.f, 0.f, 0.f, 0.f};

    // L1 sweep: windows kq (h0), kq+8 (h0), kq+16 (h1), kq+24 (h1).
    // A0s/A1s hold the h0 fragments and stay live for the L0 sweep.
    i32x8 A0s[4], A1s[4], A2s[4], A3s[4];
    i32x4 B0s[4], B1s[4];
    ld_A(a0, 16, kq, A0s);       ld_B(p0, kq, B0s);
    ld_A(a0, 16, kq + 8, A1s);   ld_B(p0, kq + 8, B1s);
    ld_A(a1, 16, kq, A2s);       // h1 window kq+16 -> a1 local window kq
    mfma_set(acc, A0s, B0s);
    ld_B(p1, kq, B0s);           // U1 window kq (for A2s)
    ld_A(a1, 16, kq + 8, A3s);   // h1 window kq+24
    mfma_set(acc, A1s, B1s);
    ld_B(p1, kq + 8, B1s);       // U1 window kq+8 (for A3s)
    mfma_set(acc, A2s, B0s);
    mfma_set(acc, A3s, B1s);

    // L0 B prefetch (hides under L1 epilogue): U0 windows kq, kq+8; wave0: x+W0
    i32x4 PB0[4], PB1[4], PBX[4];
    i32x8 PAX[4];
    if (hasL0) {
        ld_B(l0b1, kq, PB0);
        ld_B(l0b1, kq + 8, PB1);
        if (kq == 0) {
            ld_A(l0x, 1, 0, PAX);
            ld_B(l0b0, 0, PBX);
        }
    }

    // L1 epilogue (4 barriers)
    epilogue(acc, b1, c1, h1out, zs, ut, mh, tid, lane, kq);

    // L0 sweep: wave kq computes L0 windows kq+1 (=h0[kq], in A0s) and
    // kq+9 (=h0[kq+8], in A1s); wave 0 additionally window 0 (x, PAX).
    if (hasL0) {
#pragma unroll
        for (int g = 0; g < 4; ++g)
#pragma unroll
            for (int mt = 0; mt < 4; ++mt) acc[g][mt] = f32x4{0.f, 0.f, 0.f, 0.f};

        mfma_set(acc, A0s, PB0);
        mfma_set(acc, A1s, PB1);
        if (kq == 0) mfma_set(acc, PAX, PBX);

        epilogue(acc, b0, c0, h0next, zs, ut, mh, tid, lane, kq);
    }
}

// ---------------- head: y = relu((h1 @ Wd)/1024 + bd); fp8 x fp4 ------------
__global__ __launch_bounds__(256)
void head_mfma(const unsigned char* __restrict__ h1p,
               const unsigned char* __restrict__ Wdp,
               const float* __restrict__ bd, float* __restrict__ y) {
    const int lane = threadIdx.x & 63;
    const int w    = threadIdx.x >> 6;  // k-split wave
    const int ut   = blockIdx.x & 127;
    const int mh   = blockIdx.x >> 7;

    const unsigned char* ap = h1p + ((size_t)(mh * 4) * 16) * 2048 + lane * 32;
    const unsigned char* wp = Wdp + ((size_t)(ut * 16)) * 1024 + lane * 16;

    f32x4 acc[4];
#pragma unroll
    for (int mt = 0; mt < 4; ++mt) acc[mt] = f32x4{0.f, 0.f, 0.f, 0.f};

#pragma unroll
    for (int wi = 0; wi < 4; ++wi) {
        const int W = w + wi * 4;
        i32x4 bq = *reinterpret_cast<const i32x4*>(wp + (size_t)W * 1024);
        i32x8 bf = {bq[0], bq[1], bq[2], bq[3], 0, 0, 0, 0};
#pragma unroll
        for (int mt = 0; mt < 4; ++mt) {
            i32x8 a = *reinterpret_cast<const i32x8*>(ap + (size_t)(mt * 16 + W) * 2048);
            acc[mt] = __builtin_amdgcn_mfma_scale_f32_16x16x128_f8f6f4(
                a, bf, acc[mt], 0, 4, 0, SCL1_, 0, SCL1_);
        }
    }

    __shared__ float zs[4][64][17];
#pragma unroll
    for (int mt = 0; mt < 4; ++mt)
#pragma unroll
        for (int r = 0; r < 4; ++r)
            zs[w][mt * 16 + (lane >> 4) * 4 + r][lane & 15] = acc[mt][r];
    __syncthreads();

    const int tid = threadIdx.x;
    const int lr  = tid >> 2;
    const int u4  = (tid & 3) * 4;
    const int grow = mh * 64 + lr;
    const int gu   = ut * 16 + u4;

    float4 r;
    float* rr = &r.x;
#pragma unroll
    for (int e = 0; e < 4; ++e) {
        float v = (zs[0][lr][u4 + e] + zs[1][lr][u4 + e] +
                   zs[2][lr][u4 + e] + zs[3][lr][u4 + e]) * INV_S_ + bd[gu + e];
        rr[e] = v > 0.f ? v : 0.f;
    }
    *reinterpret_cast<float4*>(&y[(size_t)grow * U_ + gu]) = r;
}

// ---------------- out[b] = sigmoid(y[b,:] @ Wo + bo) ----------------
__global__ __launch_bounds__(256)
void head2(const float* __restrict__ y, const float* __restrict__ Wo,
           const float* __restrict__ bo, float* __restrict__ out) {
    __shared__ float red[256];
    const int b = blockIdx.x;
    const int tid = threadIdx.x;
    float s = 0.f;
    for (int u = tid; u < U_; u += 256) s += y[(size_t)b * U_ + u] * Wo[u];
    red[tid] = s;
    __syncthreads();
    for (int off = 128; off > 0; off >>= 1) {
        if (tid < off) red[tid] += red[tid + off];
        __syncthreads();
    }
    if (tid == 0) out[b] = 1.f / (1.f + __expf(-(red[0] + bo[0])));
}

extern "C" void kernel_launch(void* const* d_in, const int* in_sizes, int n_in,
                              void* d_out, int out_size, void* d_ws, size_t ws_size,
                              hipStream_t stream) {
    const int*   tokens = (const int*)  d_in[0];
    const float* emb    = (const float*)d_in[1];
    const float* W0     = (const float*)d_in[2];
    const float* U0     = (const float*)d_in[3];
    const float* b0     = (const float*)d_in[4];
    const float* W1     = (const float*)d_in[5];
    const float* U1     = (const float*)d_in[6];
    const float* b1     = (const float*)d_in[7];
    const float* Wd     = (const float*)d_in[8];
    const float* bd     = (const float*)d_in[9];
    const float* Wo     = (const float*)d_in[10];
    const float* bo     = (const float*)d_in[11];

    // ws layout (bytes); total ~32 MB
    char* base = (char*)d_ws;
    unsigned char* h0a = (unsigned char*)(base + 0);         // 256 KB (fp8 frag128)
    unsigned char* h1a = (unsigned char*)(base + 262144);    // 256 KB
    float*         c0  = (float*)        (base + 524288);    // 1 MB
    float*         c1  = (float*)        (base + 1572864);   // 1 MB
    unsigned char* h0b = (unsigned char*)(base + 2621440);   // 256 KB
    unsigned char* h1b = (unsigned char*)(base + 2883584);   // 256 KB
    unsigned char* Xp  = (unsigned char*)(base + 3145728);   // 1.25 MB
    float*         yb  = (float*)        (base + 3145728);   // overlays Xp (dead by head)
    unsigned char* W0p = (unsigned char*)(base + 4456448);   // 512 KB (fp4)
    unsigned char* U0p = (unsigned char*)(base + 4980736);   // 8 MB (fp4)
    unsigned char* W1p = (unsigned char*)(base + 13369344);  // 8 MB (fp4)
    unsigned char* U1p = (unsigned char*)(base + 21757952);  // 8 MB (fp4)
    unsigned char* Wdp = (unsigned char*)(base + 30146560);  // 2 MB (fp4)

    // zero h0a, h1a, c0, c1 (contiguous 2.56 MB)
    hipMemsetAsync(d_ws, 0, 2621440, stream);

    embed_pack<<<(T_ * 8 * 64 * 4 + 255) / 256, 256, 0, stream>>>(tokens, emb, Xp);
    pack_all<<<6784, 256, 0, stream>>>(W0, U0, W1, U1, Wd,
                                       W0p, U0p, W1p, U1p, Wdp);

    // prologue: L0(0): x(0) + h0a(=0) -> h0b
    lstm_l0_first<<<256, 512, 0, stream>>>(Xp, W0p, U0p, b0, c0, h0a, h0b);

    // fused phases: phase k = { L1(k), L0(k+1) }
    for (int k = 0; k < T_; ++k) {
        const unsigned char* h0cur  = (k & 1) ? h0a : h0b;
        unsigned char*       h0next = (k & 1) ? h0b : h0a;   // written for k+1
        const unsigned char* h1in   = (k & 1) ? h1b : h1a;
        unsigned char*       h1out  = (k & 1) ? h1a : h1b;
        lstm_phase<<<256, 512, 0, stream>>>(Xp, W0p, U0p, W1p, U1p,
                                            b0, b1, c0, c1,
                                            h0cur, h0next, h1in, h1out, k);
    }
    // h1(79): 79 odd -> h1a
    head_mfma<<<256, 256, 0, stream>>>(h1a, Wdp, bd, yb);
    head2<<<B_, 256, 0, stream>>>(yb, Wo, bo, (float*)d_out);
}